// Round 1
// baseline (156.434 us; speedup 1.0000x reference)
//
#include <hip/hip_runtime.h>
#include <math.h>

// AdderModel: B=16384 rows, T=64 tokens (== wavefront), D=3, HD=4, FF=2, VOCAB=10.
// One wave per row, lane == token index t. Attention inner loop broadcasts
// k[s], v[s] across the wave via v_readlane (uniform s, fully unrolled).

namespace {
constexpr int kB = 16384;
constexpr int kT = 64;
constexpr int kVocab = 10;
constexpr float kEps = 1e-6f;

__device__ __forceinline__ float readlane_f(float x, int s) {
    return __uint_as_float((unsigned)__builtin_amdgcn_readlane((int)__float_as_uint(x), s));
}

__global__ __launch_bounds__(256, 4) void adder_model_kernel(
    const int* __restrict__ idx,
    const float* __restrict__ p_arcA,
    const float* __restrict__ p_arcStart,
    const float* __restrict__ p_arcStride,
    const float* __restrict__ w_ln1,
    const float* __restrict__ w_ln2,
    const float* __restrict__ w_lnf,
    const float* __restrict__ w_qn,
    const float* __restrict__ Wq,
    const float* __restrict__ Wk,
    const float* __restrict__ Wg,
    const float* __restrict__ Wu,
    const float* __restrict__ Wd,
    float* __restrict__ out)
{
    __shared__ float table_s[kVocab * 2];

    const int lane = threadIdx.x & 63;
    const int wid  = threadIdx.x >> 6;

    const float A  = p_arcA[0];
    const float a0 = p_arcStart[0];
    const float da = p_arcStride[0];

    if (threadIdx.x < kVocab) {
        float ang = a0 + (float)threadIdx.x * da;
        table_s[2 * threadIdx.x]     = A * cosf(ang);
        table_s[2 * threadIdx.x + 1] = A * sinf(ang);
    }
    __syncthreads();

    // Register mirror of the table for the epilogue logits (static indexing only).
    float tb[2 * kVocab];
#pragma unroll
    for (int d = 0; d < 2 * kVocab; ++d) tb[d] = table_s[d];

    // Per-lane (per-token) constants: positional encoding + RoPE angles.
    const float t_f = (float)lane;
    const float pe  = sinf(t_f * __expf(-logf(10000.0f)));
    const float c0  = cosf(t_f);
    const float s0  = sinf(t_f);
    const float ang1 = t_f * 0.57735026918962576f;  // t * 3^-0.5
    const float c1  = cosf(ang1);
    const float s1  = sinf(ang1);

    // Weights: uniform addresses -> scalar loads (SGPRs).
    const float wl1_0 = w_ln1[0], wl1_1 = w_ln1[1], wl1_2 = w_ln1[2];
    const float wl2_0 = w_ln2[0], wl2_1 = w_ln2[1], wl2_2 = w_ln2[2];
    const float wlf0 = w_lnf[0], wlf1 = w_lnf[1];  // w_lnf[2] multiplies a discarded comp
    const float wqn0 = w_qn[0], wqn1 = w_qn[1], wqn2 = w_qn[2], wqn3 = w_qn[3];
    const float Wq00 = Wq[0],  Wq01 = Wq[1],  Wq02 = Wq[2];
    const float Wq10 = Wq[3],  Wq11 = Wq[4],  Wq12 = Wq[5];
    const float Wq20 = Wq[6],  Wq21 = Wq[7],  Wq22 = Wq[8];
    const float Wq30 = Wq[9],  Wq31 = Wq[10], Wq32 = Wq[11];
    const float Wk00 = Wk[0],  Wk01 = Wk[1],  Wk02 = Wk[2];
    const float Wk10 = Wk[3],  Wk11 = Wk[4],  Wk12 = Wk[5];
    const float Wk20 = Wk[6],  Wk21 = Wk[7],  Wk22 = Wk[8];
    const float Wk30 = Wk[9],  Wk31 = Wk[10], Wk32 = Wk[11];
    const float Wg00 = Wg[0],  Wg01 = Wg[1],  Wg02 = Wg[2];
    const float Wg10 = Wg[3],  Wg11 = Wg[4],  Wg12 = Wg[5];
    const float Wu00 = Wu[0],  Wu01 = Wu[1],  Wu02 = Wu[2];
    const float Wu10 = Wu[3],  Wu11 = Wu[4],  Wu12 = Wu[5];
    const float Wd00 = Wd[0],  Wd01 = Wd[1];
    const float Wd10 = Wd[2],  Wd11 = Wd[3];
    const float Wd20 = Wd[4],  Wd21 = Wd[5];

    const int nwaves = (int)(gridDim.x * (blockDim.x >> 6));
    const int gw     = (int)(blockIdx.x * (blockDim.x >> 6)) + wid;

    for (int row = gw; row < kB; row += nwaves) {
        const int tix = idx[(size_t)row * kT + lane];
        const float x0i = table_s[2 * tix];
        const float x1i = table_s[2 * tix + 1];
        const float x2i = pe;

        // RMSNorm 1
        const float r1 = rsqrtf((x0i*x0i + x1i*x1i + x2i*x2i) * (1.0f/3.0f) + kEps);
        const float h0 = x0i * r1 * wl1_0;
        const float h1 = x1i * r1 * wl1_1;
        const float h2 = x2i * r1 * wl1_2;

        // q/k/v projections (v == k_pre, un-normalized, un-roped)
        const float qp0 = h0*Wq00 + h1*Wq01 + h2*Wq02;
        const float qp1 = h0*Wq10 + h1*Wq11 + h2*Wq12;
        const float qp2 = h0*Wq20 + h1*Wq21 + h2*Wq22;
        const float qp3 = h0*Wq30 + h1*Wq31 + h2*Wq32;
        float v0 = h0*Wk00 + h1*Wk01 + h2*Wk02;
        float v1 = h0*Wk10 + h1*Wk11 + h2*Wk12;
        float v2 = h0*Wk20 + h1*Wk21 + h2*Wk22;
        float v3 = h0*Wk30 + h1*Wk31 + h2*Wk32;

        // q/k RMSNorm (over HD=4) with w_qn
        const float rq = rsqrtf((qp0*qp0 + qp1*qp1 + qp2*qp2 + qp3*qp3) * 0.25f + kEps);
        const float rk = rsqrtf((v0*v0 + v1*v1 + v2*v2 + v3*v3) * 0.25f + kEps);
        const float qn0 = qp0*rq*wqn0, qn1 = qp1*rq*wqn1, qn2 = qp2*rq*wqn2, qn3 = qp3*rq*wqn3;
        const float kn0 = v0*rk*wqn0,  kn1 = v1*rk*wqn1,  kn2 = v2*rk*wqn2,  kn3 = v3*rk*wqn3;

        // RoPE; fold the 1/sqrt(HD)=0.5 score scale into q
        const float q0 = (qn0*c0 - qn1*s0) * 0.5f;
        const float q1 = (qn0*s0 + qn1*c0) * 0.5f;
        const float q2 = (qn2*c1 - qn3*s1) * 0.5f;
        const float q3 = (qn2*s1 + qn3*c1) * 0.5f;
        float k0 = kn0*c0 - kn1*s0;
        float k1 = kn0*s0 + kn1*c0;
        float k2 = kn2*c1 - kn3*s1;
        float k3 = kn2*s1 + kn3*c1;

        // Causal attention. No max-subtraction needed: |score| <= ~4 (rms-normed
        // q,k times w_qn, scale 0.5), exp stays in [e-4, e4] -> fp32-safe, and
        // softmax is shift-invariant.
        float l = 0.0f, o0 = 0.0f, o1 = 0.0f, o2 = 0.0f, o3 = 0.0f;
#pragma unroll
        for (int s = 0; s < kT; ++s) {
            const float k0s = readlane_f(k0, s);
            const float k1s = readlane_f(k1, s);
            const float k2s = readlane_f(k2, s);
            const float k3s = readlane_f(k3, s);
            const float v0s = readlane_f(v0, s);
            const float v1s = readlane_f(v1, s);
            const float v2s = readlane_f(v2, s);
            const float v3s = readlane_f(v3, s);
            const float sc = q0*k0s + q1*k1s + q2*k2s + q3*k3s;
            float e = __expf(sc);
            e = (s <= lane) ? e : 0.0f;
            l  += e;
            o0 += e * v0s;
            o1 += e * v1s;
            o2 += e * v2s;
            o3 += e * v3s;
        }

        const float invl = 1.0f / l;
        o0 *= invl; o1 *= invl; o2 *= invl; o3 *= invl;

        // Attention out-projection: x += o @ Wq   (note: Wq, not Wq.T)
        const float xa0 = x0i + o0*Wq00 + o1*Wq10 + o2*Wq20 + o3*Wq30;
        const float xa1 = x1i + o0*Wq01 + o1*Wq11 + o2*Wq21 + o3*Wq31;
        const float xa2 = x2i + o0*Wq02 + o1*Wq12 + o2*Wq22 + o3*Wq32;

        // MLP with RMSNorm 2
        const float r2 = rsqrtf((xa0*xa0 + xa1*xa1 + xa2*xa2) * (1.0f/3.0f) + kEps);
        const float hh0 = xa0*r2*wl2_0, hh1 = xa1*r2*wl2_1, hh2 = xa2*r2*wl2_2;
        const float g0 = hh0*Wg00 + hh1*Wg01 + hh2*Wg02;
        const float g1 = hh0*Wg10 + hh1*Wg11 + hh2*Wg12;
        const float u0 = hh0*Wu00 + hh1*Wu01 + hh2*Wu02;
        const float u1 = hh0*Wu10 + hh1*Wu11 + hh2*Wu12;
        const float f0 = g0 / (1.0f + __expf(-g0)) * u0;   // silu(g)*u
        const float f1 = g1 / (1.0f + __expf(-g1)) * u1;
        const float xf0 = xa0 + f0*Wd00 + f1*Wd01;
        const float xf1 = xa1 + f0*Wd10 + f1*Wd11;
        const float xf2 = xa2 + f0*Wd20 + f1*Wd21;

        // Final RMSNorm; only comps 0,1 feed the logits
        const float rf = rsqrtf((xf0*xf0 + xf1*xf1 + xf2*xf2) * (1.0f/3.0f) + kEps);
        const float y0 = xf0 * rf * wlf0;
        const float y1 = xf1 * rf * wlf1;

        // Logits: y[:2] @ table.T  -> 10 floats/lane, contiguous, 8B-aligned.
        float2* op = (float2*)(out + (size_t)(row * kT + lane) * kVocab);
#pragma unroll
        for (int d = 0; d < kVocab / 2; ++d) {
            float2 o2v;
            o2v.x = y0 * tb[4*d]     + y1 * tb[4*d + 1];
            o2v.y = y0 * tb[4*d + 2] + y1 * tb[4*d + 3];
            op[d] = o2v;
        }
    }
}
}  // namespace

extern "C" void kernel_launch(void* const* d_in, const int* in_sizes, int n_in,
                              void* d_out, int out_size, void* d_ws, size_t ws_size,
                              hipStream_t stream) {
    (void)in_sizes; (void)n_in; (void)d_ws; (void)ws_size; (void)out_size;
    const int*   idx       = (const int*)  d_in[0];
    const float* arcA      = (const float*)d_in[1];
    const float* arcStart  = (const float*)d_in[2];
    const float* arcStride = (const float*)d_in[3];
    const float* w_ln1     = (const float*)d_in[4];
    const float* w_ln2     = (const float*)d_in[5];
    const float* w_lnf     = (const float*)d_in[6];
    const float* w_qn      = (const float*)d_in[7];
    const float* Wq        = (const float*)d_in[8];
    const float* Wk        = (const float*)d_in[9];
    const float* Wg        = (const float*)d_in[10];
    const float* Wu        = (const float*)d_in[11];
    const float* Wd        = (const float*)d_in[12];
    float* out = (float*)d_out;

    // 2048 blocks x 256 threads = 8192 waves; 2 rows per wave (grid-stride),
    // amortizing per-lane trig + weight loads across rows.
    dim3 grid(2048), block(256);
    hipLaunchKernelGGL(adder_model_kernel, grid, block, 0, stream,
                       idx, arcA, arcStart, arcStride,
                       w_ln1, w_ln2, w_lnf, w_qn, Wq, Wk, Wg, Wu, Wd, out);
}

// Round 2
// 113.836 us; speedup vs baseline: 1.3742x; 1.3742x over previous
//
#include <hip/hip_runtime.h>
#include <math.h>

// AdderModel: B=16384 rows, T=64 tokens (== wavefront), D=3, HD=4, FF=2, VOCAB=10.
// One wave per row, lane == token index t. Round 2: k/v broadcast through
// wave-private LDS (uniform-address ds_read_b128, conflict-free broadcast)
// instead of v_readlane (VALU->SGPR->VALU hazards made round 1 ~9000 cyc/row).
// Softmax in exp2 domain with 0.5*log2e folded into q; packed-f32 (v_pk_fma)
// score/accumulate.

namespace {
constexpr int kB = 16384;
constexpr int kT = 64;
constexpr int kVocab = 10;
constexpr float kEps = 1e-6f;
constexpr int kWaves = 4;  // waves per block

typedef float v2f __attribute__((ext_vector_type(2)));

__global__ __launch_bounds__(256, 6) void adder_model_kernel(
    const int* __restrict__ idx,
    const float* __restrict__ p_arcA,
    const float* __restrict__ p_arcStart,
    const float* __restrict__ p_arcStride,
    const float* __restrict__ w_ln1,
    const float* __restrict__ w_ln2,
    const float* __restrict__ w_lnf,
    const float* __restrict__ w_qn,
    const float* __restrict__ Wq,
    const float* __restrict__ Wk,
    const float* __restrict__ Wg,
    const float* __restrict__ Wu,
    const float* __restrict__ Wd,
    float* __restrict__ out)
{
    __shared__ float4 kArr[kWaves][kT];   // roped, rms-normed k per token
    __shared__ float4 vArr[kWaves][kT];   // v (= raw Wk projection) per token
    __shared__ float table_s[kVocab * 2];

    const int lane = threadIdx.x & 63;
    const int wid  = threadIdx.x >> 6;

    if (threadIdx.x < kVocab) {
        const float ang = p_arcStart[0] + (float)threadIdx.x * p_arcStride[0];
        const float A = p_arcA[0];
        table_s[2 * threadIdx.x]     = A * __cosf(ang);
        table_s[2 * threadIdx.x + 1] = A * __sinf(ang);
    }
    __syncthreads();

    // Register mirror of the table for the epilogue logits (static indexing).
    float tb[2 * kVocab];
#pragma unroll
    for (int d = 0; d < 2 * kVocab; ++d) tb[d] = table_s[d];

    // Per-lane (per-token) constants: positional encoding + RoPE angles.
    const float t_f = (float)lane;
    const float pe  = __sinf(t_f * 1e-4f);          // sin(t * exp(-ln 1e4))
    const float c0  = __cosf(t_f);
    const float s0  = __sinf(t_f);
    const float ang1 = t_f * 0.57735026918962576f;  // t * 3^-0.5
    const float c1  = __cosf(ang1);
    const float s1  = __sinf(ang1);

    // Weights: uniform addresses -> scalar loads (SGPRs).
    const float wl1_0 = w_ln1[0], wl1_1 = w_ln1[1], wl1_2 = w_ln1[2];
    const float wl2_0 = w_ln2[0], wl2_1 = w_ln2[1], wl2_2 = w_ln2[2];
    const float wlf0 = w_lnf[0], wlf1 = w_lnf[1];   // w_lnf[2] feeds a dropped comp
    const float wqn0 = w_qn[0], wqn1 = w_qn[1], wqn2 = w_qn[2], wqn3 = w_qn[3];
    const float Wq00 = Wq[0],  Wq01 = Wq[1],  Wq02 = Wq[2];
    const float Wq10 = Wq[3],  Wq11 = Wq[4],  Wq12 = Wq[5];
    const float Wq20 = Wq[6],  Wq21 = Wq[7],  Wq22 = Wq[8];
    const float Wq30 = Wq[9],  Wq31 = Wq[10], Wq32 = Wq[11];
    const float Wk00 = Wk[0],  Wk01 = Wk[1],  Wk02 = Wk[2];
    const float Wk10 = Wk[3],  Wk11 = Wk[4],  Wk12 = Wk[5];
    const float Wk20 = Wk[6],  Wk21 = Wk[7],  Wk22 = Wk[8];
    const float Wk30 = Wk[9],  Wk31 = Wk[10], Wk32 = Wk[11];
    const float Wg00 = Wg[0],  Wg01 = Wg[1],  Wg02 = Wg[2];
    const float Wg10 = Wg[3],  Wg11 = Wg[4],  Wg12 = Wg[5];
    const float Wu00 = Wu[0],  Wu01 = Wu[1],  Wu02 = Wu[2];
    const float Wu10 = Wu[3],  Wu11 = Wu[4],  Wu12 = Wu[5];
    const float Wd00 = Wd[0],  Wd01 = Wd[1];
    const float Wd10 = Wd[2],  Wd11 = Wd[3];
    const float Wd20 = Wd[4],  Wd21 = Wd[5];

    const int row = (int)blockIdx.x * kWaves + wid;   // 4096 blocks x 4 waves == 16384

    const int tix = idx[(size_t)row * kT + lane];
    const float x0i = table_s[2 * tix];
    const float x1i = table_s[2 * tix + 1];
    const float x2i = pe;

    // RMSNorm 1
    const float r1 = __builtin_amdgcn_rsqf((x0i*x0i + x1i*x1i + x2i*x2i) * (1.0f/3.0f) + kEps);
    const float h0 = x0i * r1 * wl1_0;
    const float h1 = x1i * r1 * wl1_1;
    const float h2 = x2i * r1 * wl1_2;

    // q/k/v projections (v == k_pre, un-normalized, un-roped)
    const float qp0 = h0*Wq00 + h1*Wq01 + h2*Wq02;
    const float qp1 = h0*Wq10 + h1*Wq11 + h2*Wq12;
    const float qp2 = h0*Wq20 + h1*Wq21 + h2*Wq22;
    const float qp3 = h0*Wq30 + h1*Wq31 + h2*Wq32;
    const float v0 = h0*Wk00 + h1*Wk01 + h2*Wk02;
    const float v1 = h0*Wk10 + h1*Wk11 + h2*Wk12;
    const float v2 = h0*Wk20 + h1*Wk21 + h2*Wk22;
    const float v3 = h0*Wk30 + h1*Wk31 + h2*Wk32;

    // q/k RMSNorm (over HD=4) with w_qn
    const float rq = __builtin_amdgcn_rsqf((qp0*qp0 + qp1*qp1 + qp2*qp2 + qp3*qp3) * 0.25f + kEps);
    const float rk = __builtin_amdgcn_rsqf((v0*v0 + v1*v1 + v2*v2 + v3*v3) * 0.25f + kEps);
    const float qn0 = qp0*rq*wqn0, qn1 = qp1*rq*wqn1, qn2 = qp2*rq*wqn2, qn3 = qp3*rq*wqn3;
    const float kn0 = v0*rk*wqn0,  kn1 = v1*rk*wqn1,  kn2 = v2*rk*wqn2,  kn3 = v3*rk*wqn3;

    // RoPE; fold 1/sqrt(HD)=0.5 AND log2(e) into q -> scores in exp2 domain.
    constexpr float kQS = 0.72134752044448170f;  // 0.5 * log2(e)
    const float q0 = (qn0*c0 - qn1*s0) * kQS;
    const float q1 = (qn0*s0 + qn1*c0) * kQS;
    const float q2 = (qn2*c1 - qn3*s1) * kQS;
    const float q3 = (qn2*s1 + qn3*c1) * kQS;
    const float k0 = kn0*c0 - kn1*s0;
    const float k1 = kn0*s0 + kn1*c0;
    const float k2 = kn2*c1 - kn3*s1;
    const float k3 = kn2*s1 + kn3*c1;

    kArr[wid][lane] = make_float4(k0, k1, k2, k3);
    vArr[wid][lane] = make_float4(v0, v1, v2, v3);
    __syncthreads();   // orders lane-crossing LDS writes->reads (all waves reach it)

    // Causal attention, exp2 domain. Masked scores -> -inf -> exp2 gives 0.
    const v2f q01 = {q0, q1}, q23 = {q2, q3};
    v2f o01 = {0.0f, 0.0f}, o23 = {0.0f, 0.0f};
    float l = 0.0f;
    const float4* __restrict__ kp = kArr[wid];
    const float4* __restrict__ vp = vArr[wid];
#pragma unroll
    for (int s = 0; s < kT; ++s) {
        const float4 kk = kp[s];   // uniform address: LDS broadcast, no conflicts
        const float4 vv = vp[s];
        v2f p = q01 * v2f{kk.x, kk.y} + q23 * v2f{kk.z, kk.w};
        float sc = p.x + p.y;
        sc = (s <= lane) ? sc : -INFINITY;
        const float e = __builtin_amdgcn_exp2f(sc);
        l += e;
        const v2f e2 = {e, e};
        o01 += e2 * v2f{vv.x, vv.y};
        o23 += e2 * v2f{vv.z, vv.w};
    }

    const float invl = __builtin_amdgcn_rcpf(l);
    const float o0 = o01.x * invl, o1 = o01.y * invl;
    const float o2 = o23.x * invl, o3 = o23.y * invl;

    // Attention out-projection: x += o @ Wq   (note: Wq, not Wq.T)
    const float xa0 = x0i + o0*Wq00 + o1*Wq10 + o2*Wq20 + o3*Wq30;
    const float xa1 = x1i + o0*Wq01 + o1*Wq11 + o2*Wq21 + o3*Wq31;
    const float xa2 = x2i + o0*Wq02 + o1*Wq12 + o2*Wq22 + o3*Wq32;

    // MLP with RMSNorm 2
    const float r2 = __builtin_amdgcn_rsqf((xa0*xa0 + xa1*xa1 + xa2*xa2) * (1.0f/3.0f) + kEps);
    const float hh0 = xa0*r2*wl2_0, hh1 = xa1*r2*wl2_1, hh2 = xa2*r2*wl2_2;
    const float g0 = hh0*Wg00 + hh1*Wg01 + hh2*Wg02;
    const float g1 = hh0*Wg10 + hh1*Wg11 + hh2*Wg12;
    const float u0 = hh0*Wu00 + hh1*Wu01 + hh2*Wu02;
    const float u1 = hh0*Wu10 + hh1*Wu11 + hh2*Wu12;
    // silu(g)*u via exp2: sigmoid(g) = 1/(1+2^(-g*log2e))
    constexpr float kL2E = 1.4426950408889634f;
    const float f0 = g0 * __builtin_amdgcn_rcpf(1.0f + __builtin_amdgcn_exp2f(-g0 * kL2E)) * u0;
    const float f1 = g1 * __builtin_amdgcn_rcpf(1.0f + __builtin_amdgcn_exp2f(-g1 * kL2E)) * u1;
    const float xf0 = xa0 + f0*Wd00 + f1*Wd01;
    const float xf1 = xa1 + f0*Wd10 + f1*Wd11;
    const float xf2 = xa2 + f0*Wd20 + f1*Wd21;

    // Final RMSNorm; only comps 0,1 feed the logits
    const float rf = __builtin_amdgcn_rsqf((xf0*xf0 + xf1*xf1 + xf2*xf2) * (1.0f/3.0f) + kEps);
    const float y0 = xf0 * rf * wlf0;
    const float y1 = xf1 * rf * wlf1;

    // Logits: y[:2] @ table.T -> 10 floats/lane, contiguous, 8B-aligned.
    float2* op = (float2*)(out + (size_t)(row * kT + lane) * kVocab);
#pragma unroll
    for (int d = 0; d < kVocab / 2; ++d) {
        float2 o2v;
        o2v.x = y0 * tb[4*d]     + y1 * tb[4*d + 1];
        o2v.y = y0 * tb[4*d + 2] + y1 * tb[4*d + 3];
        op[d] = o2v;
    }
}
}  // namespace

extern "C" void kernel_launch(void* const* d_in, const int* in_sizes, int n_in,
                              void* d_out, int out_size, void* d_ws, size_t ws_size,
                              hipStream_t stream) {
    (void)in_sizes; (void)n_in; (void)d_ws; (void)ws_size; (void)out_size;
    const int*   idx       = (const int*)  d_in[0];
    const float* arcA      = (const float*)d_in[1];
    const float* arcStart  = (const float*)d_in[2];
    const float* arcStride = (const float*)d_in[3];
    const float* w_ln1     = (const float*)d_in[4];
    const float* w_ln2     = (const float*)d_in[5];
    const float* w_lnf     = (const float*)d_in[6];
    const float* w_qn      = (const float*)d_in[7];
    const float* Wq        = (const float*)d_in[8];
    const float* Wk        = (const float*)d_in[9];
    const float* Wg        = (const float*)d_in[10];
    const float* Wu        = (const float*)d_in[11];
    const float* Wd        = (const float*)d_in[12];
    float* out = (float*)d_out;

    // 4096 blocks x 256 threads = 16384 waves = 1 row per wave, exact cover.
    dim3 grid(4096), block(256);
    hipLaunchKernelGGL(adder_model_kernel, grid, block, 0, stream,
                       idx, arcA, arcStart, arcStride,
                       w_ln1, w_ln2, w_lnf, w_qn, Wq, Wk, Wg, Wu, Wd, out);
}

// Round 4
// 112.813 us; speedup vs baseline: 1.3867x; 1.0091x over previous
//
#include <hip/hip_runtime.h>
#include <math.h>

// AdderModel: B=16384 rows, T=64 (== wave), D=3, HD=4, FF=2, VOCAB=10.
// Round 4 = round 3 with a compile fix: manual RNE bf16 pack instead of
// __hip_bfloat162 bit_cast (not trivially copyable on this ROCm).
// Attention via MFMA (32x32x16 bf16): round-2 profile showed the 128
// uniform-address ds_read_b128/row broadcast loop saturates the LDS pipe
// (~41 us/CU); MFMA is the only pipe doing 64-way exchange without LDS.
//   S^T = K.Q^T (hi/lo bf16 split, 3 MFMAs/tile -> fp32-accurate scores),
//   exp2 in C-layout, pack bf16 -> P[t][s] rows (s-contiguous b64 writes),
//   O = P.V' with V' = [v0..v3, 1] (l comes free as column 4).

namespace {
constexpr int kVocab = 10;
constexpr float kEps = 1e-6f;
constexpr int kWaves = 4;

typedef __attribute__((ext_vector_type(8)))  short short8;
typedef __attribute__((ext_vector_type(16))) float float16;

// Per-wave LDS region (bytes). Frag buffers die before Olds is written -> alias.
constexpr int kOffQh  = 0;      // uint2[64]  bf16x4 q-hi
constexpr int kOffQl  = 512;    // uint2[64]  q-lo
constexpr int kOffKh  = 1024;   // uint2[64]  k-hi
constexpr int kOffKl  = 1536;   // uint2[64]  k-lo
constexpr int kOffO   = 0;      // float[5][76]  (aliases frag buffers, 1520 B)
constexpr int kOffP   = 2048;   // ushort[64][72] exp'd scores, bf16 (9216 B)
constexpr int kOffVt  = 11264;  // ushort[8][72]  V transposed + ones row (1152 B)
constexpr int kWaveLds = 12544; // multiple of 16
constexpr int kPP = 72;         // P/Vt row pitch in shorts (144 B: 16B-aligned rows)
constexpr int kOP = 76;         // Olds row pitch in floats (304 B)

// Round-to-nearest-even f32 -> bf16 (finite inputs only; exact RNE).
__device__ __forceinline__ unsigned bf16_rn(float x) {
    const unsigned u = __float_as_uint(x);
    return (u + 0x7fffu + ((u >> 16) & 1u)) >> 16;
}
__device__ __forceinline__ unsigned pk_bf16(float a, float b) {
    return bf16_rn(a) | (bf16_rn(b) << 16);
}
__device__ __forceinline__ float bf_lo(unsigned u) { return __uint_as_float(u << 16); }
__device__ __forceinline__ float bf_hi(unsigned u) { return __uint_as_float(u & 0xffff0000u); }

__device__ __forceinline__ float16 mfma(short8 a, short8 b, float16 c) {
    return __builtin_amdgcn_mfma_f32_32x32x16_bf16(a, b, c, 0, 0, 0);
}

// A/B fragment from a token's packed bf16x4: lanes 0-31 hold {v0..v3,0,0,0,0}
// (k=0..7), lanes 32-63 hold zeros (k=8..15).
__device__ __forceinline__ short8 tok_frag(const char* wbase, int off, int tok, bool lo_half) {
    uint2 r = *(const uint2*)(wbase + off + tok * 8);
    uint4 t;
    t.x = lo_half ? r.x : 0u;
    t.y = lo_half ? r.y : 0u;
    t.z = 0u; t.w = 0u;
    return __builtin_bit_cast(short8, t);
}

// exp2 a score tile (C layout) and store bf16 into P[t][s]. S^T tile (TM,TN):
// s = TM*32 + (reg&3) + 8*(reg>>2) + 4*h, t = TN*32 + (lane&31).
template<int TM, int TN, bool MASKED>
__device__ __forceinline__ void exp_store(const float16& S, ushort* P, int tloc, int h, int m) {
    const int t = TN * 32 + tloc;
#pragma unroll
    for (int c = 0; c < 4; ++c) {
        float e[4];
#pragma unroll
        for (int j = 0; j < 4; ++j) {
            float sc = S[4 * c + j];
            if (MASKED) sc = ((j + 8 * c) <= m) ? sc : -INFINITY;  // exp2(-inf)=0
            e[j] = __builtin_amdgcn_exp2f(sc);
        }
        uint2 w;
        w.x = pk_bf16(e[0], e[1]);
        w.y = pk_bf16(e[2], e[3]);
        *(uint2*)(P + t * kPP + TM * 32 + 8 * c + 4 * h) = w;
    }
}

__global__ __launch_bounds__(256, 3) void adder_model_kernel(
    const int* __restrict__ idx,
    const float* __restrict__ p_arcA,
    const float* __restrict__ p_arcStart,
    const float* __restrict__ p_arcStride,
    const float* __restrict__ w_ln1,
    const float* __restrict__ w_ln2,
    const float* __restrict__ w_lnf,
    const float* __restrict__ w_qn,
    const float* __restrict__ Wq,
    const float* __restrict__ Wk,
    const float* __restrict__ Wg,
    const float* __restrict__ Wu,
    const float* __restrict__ Wd,
    float* __restrict__ out)
{
    __shared__ __align__(16) char smem[kWaves][kWaveLds];
    __shared__ float table_s[kVocab * 2];

    const int lane = threadIdx.x & 63;
    const int wid  = threadIdx.x >> 6;
    char* wbase = &smem[wid][0];

    if (threadIdx.x < kVocab) {
        const float ang = p_arcStart[0] + (float)threadIdx.x * p_arcStride[0];
        const float A = p_arcA[0];
        table_s[2 * threadIdx.x]     = A * __cosf(ang);
        table_s[2 * threadIdx.x + 1] = A * __sinf(ang);
    }
    __syncthreads();

    float tb[2 * kVocab];
#pragma unroll
    for (int d = 0; d < 2 * kVocab; ++d) tb[d] = table_s[d];

    // Per-token constants
    const float t_f = (float)lane;
    const float pe  = __sinf(t_f * 1e-4f);
    const float c0  = __cosf(t_f);
    const float s0  = __sinf(t_f);
    const float ang1 = t_f * 0.57735026918962576f;
    const float c1  = __cosf(ang1);
    const float s1  = __sinf(ang1);

    // Scalar weight loads
    const float wl1_0 = w_ln1[0], wl1_1 = w_ln1[1], wl1_2 = w_ln1[2];
    const float wl2_0 = w_ln2[0], wl2_1 = w_ln2[1], wl2_2 = w_ln2[2];
    const float wlf0 = w_lnf[0], wlf1 = w_lnf[1];
    const float wqn0 = w_qn[0], wqn1 = w_qn[1], wqn2 = w_qn[2], wqn3 = w_qn[3];
    const float Wq00 = Wq[0],  Wq01 = Wq[1],  Wq02 = Wq[2];
    const float Wq10 = Wq[3],  Wq11 = Wq[4],  Wq12 = Wq[5];
    const float Wq20 = Wq[6],  Wq21 = Wq[7],  Wq22 = Wq[8];
    const float Wq30 = Wq[9],  Wq31 = Wq[10], Wq32 = Wq[11];
    const float Wk00 = Wk[0],  Wk01 = Wk[1],  Wk02 = Wk[2];
    const float Wk10 = Wk[3],  Wk11 = Wk[4],  Wk12 = Wk[5];
    const float Wk20 = Wk[6],  Wk21 = Wk[7],  Wk22 = Wk[8];
    const float Wk30 = Wk[9],  Wk31 = Wk[10], Wk32 = Wk[11];
    const float Wg00 = Wg[0],  Wg01 = Wg[1],  Wg02 = Wg[2];
    const float Wg10 = Wg[3],  Wg11 = Wg[4],  Wg12 = Wg[5];
    const float Wu00 = Wu[0],  Wu01 = Wu[1],  Wu02 = Wu[2];
    const float Wu10 = Wu[3],  Wu11 = Wu[4],  Wu12 = Wu[5];
    const float Wd00 = Wd[0],  Wd01 = Wd[1];
    const float Wd10 = Wd[2],  Wd11 = Wd[3];
    const float Wd20 = Wd[4],  Wd21 = Wd[5];

    const int row = (int)blockIdx.x * kWaves + wid;

    const int tix = idx[(size_t)row * 64 + lane];
    const float x0i = table_s[2 * tix];
    const float x1i = table_s[2 * tix + 1];
    const float x2i = pe;

    // RMSNorm 1 + projections
    const float r1 = __builtin_amdgcn_rsqf((x0i*x0i + x1i*x1i + x2i*x2i) * (1.0f/3.0f) + kEps);
    const float h0 = x0i * r1 * wl1_0;
    const float h1 = x1i * r1 * wl1_1;
    const float h2 = x2i * r1 * wl1_2;

    const float qp0 = h0*Wq00 + h1*Wq01 + h2*Wq02;
    const float qp1 = h0*Wq10 + h1*Wq11 + h2*Wq12;
    const float qp2 = h0*Wq20 + h1*Wq21 + h2*Wq22;
    const float qp3 = h0*Wq30 + h1*Wq31 + h2*Wq32;
    const float v0 = h0*Wk00 + h1*Wk01 + h2*Wk02;
    const float v1 = h0*Wk10 + h1*Wk11 + h2*Wk12;
    const float v2 = h0*Wk20 + h1*Wk21 + h2*Wk22;
    const float v3 = h0*Wk30 + h1*Wk31 + h2*Wk32;

    const float rq = __builtin_amdgcn_rsqf((qp0*qp0 + qp1*qp1 + qp2*qp2 + qp3*qp3) * 0.25f + kEps);
    const float rk = __builtin_amdgcn_rsqf((v0*v0 + v1*v1 + v2*v2 + v3*v3) * 0.25f + kEps);
    const float qn0 = qp0*rq*wqn0, qn1 = qp1*rq*wqn1, qn2 = qp2*rq*wqn2, qn3 = qp3*rq*wqn3;
    const float kn0 = v0*rk*wqn0,  kn1 = v1*rk*wqn1,  kn2 = v2*rk*wqn2,  kn3 = v3*rk*wqn3;

    // RoPE; fold 0.5*log2(e) into q (scores land in exp2 domain)
    constexpr float kQS = 0.72134752044448170f;
    const float q0 = (qn0*c0 - qn1*s0) * kQS;
    const float q1 = (qn0*s0 + qn1*c0) * kQS;
    const float q2 = (qn2*c1 - qn3*s1) * kQS;
    const float q3 = (qn2*s1 + qn3*c1) * kQS;
    const float k0 = kn0*c0 - kn1*s0;
    const float k1 = kn0*s0 + kn1*c0;
    const float k2 = kn2*c1 - kn3*s1;
    const float k3 = kn2*s1 + kn3*c1;

    // hi/lo bf16 split of q,k; write frag source buffers (token-indexed)
    uint2 qh, ql, kh, kl;
    qh.x = pk_bf16(q0, q1); qh.y = pk_bf16(q2, q3);
    ql.x = pk_bf16(q0 - bf_lo(qh.x), q1 - bf_hi(qh.x));
    ql.y = pk_bf16(q2 - bf_lo(qh.y), q3 - bf_hi(qh.y));
    kh.x = pk_bf16(k0, k1); kh.y = pk_bf16(k2, k3);
    kl.x = pk_bf16(k0 - bf_lo(kh.x), k1 - bf_hi(kh.x));
    kl.y = pk_bf16(k2 - bf_lo(kh.y), k3 - bf_hi(kh.y));
    *(uint2*)(wbase + kOffQh + lane * 8) = qh;
    *(uint2*)(wbase + kOffQl + lane * 8) = ql;
    *(uint2*)(wbase + kOffKh + lane * 8) = kh;
    *(uint2*)(wbase + kOffKl + lane * 8) = kl;

    // V transposed (+ ones row) for the PV B-operand
    ushort* Vt = (ushort*)(wbase + kOffVt);
    Vt[0 * kPP + lane] = (ushort)bf16_rn(v0);
    Vt[1 * kPP + lane] = (ushort)bf16_rn(v1);
    Vt[2 * kPP + lane] = (ushort)bf16_rn(v2);
    Vt[3 * kPP + lane] = (ushort)bf16_rn(v3);
    Vt[4 * kPP + lane] = 0x3F80;  // bf16 1.0 -> l = sum_s P[t][s]
    __threadfence_block();  // LDS writes -> same-wave cross-lane reads

    const int tloc = lane & 31;
    const bool loh = lane < 32;
    const int h    = lane >> 5;
    const int m    = tloc - 4 * h;   // causal keep: s_local <= m

    // Fragments (token-vector form shared by A and B operands)
    const short8 aKh0 = tok_frag(wbase, kOffKh, tloc,      loh);
    const short8 aKl0 = tok_frag(wbase, kOffKl, tloc,      loh);
    const short8 aKh1 = tok_frag(wbase, kOffKh, tloc + 32, loh);
    const short8 aKl1 = tok_frag(wbase, kOffKl, tloc + 32, loh);
    const short8 bQh0 = tok_frag(wbase, kOffQh, tloc,      loh);
    const short8 bQl0 = tok_frag(wbase, kOffQl, tloc,      loh);
    const short8 bQh1 = tok_frag(wbase, kOffQh, tloc + 32, loh);
    const short8 bQl1 = tok_frag(wbase, kOffQl, tloc + 32, loh);

    // S^T tiles = K.Q^T; 3-term hi/lo product (drop lo*lo)
    float16 Z = {0,0,0,0,0,0,0,0,0,0,0,0,0,0,0,0};
    float16 S00 = mfma(aKl0, bQh0, mfma(aKh0, bQl0, mfma(aKh0, bQh0, Z)));
    float16 S01 = mfma(aKl0, bQh1, mfma(aKh0, bQl1, mfma(aKh0, bQh1, Z)));
    float16 S11 = mfma(aKl1, bQh1, mfma(aKh1, bQl1, mfma(aKh1, bQh1, Z)));

    ushort* P = (ushort*)(wbase + kOffP);
    exp_store<0, 0, true >(S00, P, tloc, h, m);  // s<32, t<32: diagonal mask
    exp_store<0, 1, false>(S01, P, tloc, h, m);  // s<32, t>=32: fully kept
    exp_store<1, 1, true >(S11, P, tloc, h, m);  // s>=32, t>=32: diagonal mask
    __threadfence_block();

    // O = P.V' : A = P[t][s] (b128 rows), B = Vt (n -> row n&7 of Vt)
    short8 vb[4];
#pragma unroll
    for (int kc = 0; kc < 4; ++kc)
        vb[kc] = __builtin_bit_cast(short8,
            *(const uint4*)(Vt + (tloc & 7) * kPP + 16 * kc + 8 * h));

    float16 acc0 = Z, acc1 = Z;
#pragma unroll
    for (int kc = 0; kc < 2; ++kc) {   // t<32 rows: P zero for s>=32
        short8 pa = __builtin_bit_cast(short8,
            *(const uint4*)(P + tloc * kPP + 16 * kc + 8 * h));
        acc0 = mfma(pa, vb[kc], acc0);
    }
#pragma unroll
    for (int kc = 0; kc < 4; ++kc) {
        short8 pa = __builtin_bit_cast(short8,
            *(const uint4*)(P + (tloc + 32) * kPP + 16 * kc + 8 * h));
        acc1 = mfma(pa, vb[kc], acc1);
    }

    // Scatter O' (cols 0..4 = o0..o3, l) to Olds[d][t]; C-layout chunks of 4
    // regs are t-contiguous -> b128 stores.
    float* Ol = (float*)(wbase + kOffO);
    if (tloc < 5) {
#pragma unroll
        for (int c = 0; c < 4; ++c) {
            float4 w0 = make_float4(acc0[4*c], acc0[4*c+1], acc0[4*c+2], acc0[4*c+3]);
            *(float4*)(Ol + tloc * kOP +      8 * c + 4 * h) = w0;
            float4 w1 = make_float4(acc1[4*c], acc1[4*c+1], acc1[4*c+2], acc1[4*c+3]);
            *(float4*)(Ol + tloc * kOP + 32 + 8 * c + 4 * h) = w1;
        }
    }
    __threadfence_block();

    const float o0r = Ol[0 * kOP + lane];
    const float o1r = Ol[1 * kOP + lane];
    const float o2r = Ol[2 * kOP + lane];
    const float o3r = Ol[3 * kOP + lane];
    const float lr  = Ol[4 * kOP + lane];

    const float invl = __builtin_amdgcn_rcpf(lr);
    const float o0 = o0r * invl, o1 = o1r * invl, o2 = o2r * invl, o3 = o3r * invl;

    // x += o @ Wq
    const float xa0 = x0i + o0*Wq00 + o1*Wq10 + o2*Wq20 + o3*Wq30;
    const float xa1 = x1i + o0*Wq01 + o1*Wq11 + o2*Wq21 + o3*Wq31;
    const float xa2 = x2i + o0*Wq02 + o1*Wq12 + o2*Wq22 + o3*Wq32;

    // MLP
    const float r2 = __builtin_amdgcn_rsqf((xa0*xa0 + xa1*xa1 + xa2*xa2) * (1.0f/3.0f) + kEps);
    const float hh0 = xa0*r2*wl2_0, hh1 = xa1*r2*wl2_1, hh2 = xa2*r2*wl2_2;
    const float g0 = hh0*Wg00 + hh1*Wg01 + hh2*Wg02;
    const float g1 = hh0*Wg10 + hh1*Wg11 + hh2*Wg12;
    const float u0 = hh0*Wu00 + hh1*Wu01 + hh2*Wu02;
    const float u1 = hh0*Wu10 + hh1*Wu11 + hh2*Wu12;
    constexpr float kL2E = 1.4426950408889634f;
    const float f0 = g0 * __builtin_amdgcn_rcpf(1.0f + __builtin_amdgcn_exp2f(-g0 * kL2E)) * u0;
    const float f1 = g1 * __builtin_amdgcn_rcpf(1.0f + __builtin_amdgcn_exp2f(-g1 * kL2E)) * u1;
    const float xf0 = xa0 + f0*Wd00 + f1*Wd01;
    const float xf1 = xa1 + f0*Wd10 + f1*Wd11;
    const float xf2 = xa2 + f0*Wd20 + f1*Wd21;

    // Final RMSNorm + logits
    const float rf = __builtin_amdgcn_rsqf((xf0*xf0 + xf1*xf1 + xf2*xf2) * (1.0f/3.0f) + kEps);
    const float y0 = xf0 * rf * wlf0;
    const float y1 = xf1 * rf * wlf1;

    float2* op = (float2*)(out + (size_t)(row * 64 + lane) * kVocab);
#pragma unroll
    for (int d = 0; d < kVocab / 2; ++d) {
        float2 o2v;
        o2v.x = y0 * tb[4*d]     + y1 * tb[4*d + 1];
        o2v.y = y0 * tb[4*d + 2] + y1 * tb[4*d + 3];
        op[d] = o2v;
    }
}
}  // namespace

extern "C" void kernel_launch(void* const* d_in, const int* in_sizes, int n_in,
                              void* d_out, int out_size, void* d_ws, size_t ws_size,
                              hipStream_t stream) {
    (void)in_sizes; (void)n_in; (void)d_ws; (void)ws_size; (void)out_size;
    const int*   idx       = (const int*)  d_in[0];
    const float* arcA      = (const float*)d_in[1];
    const float* arcStart  = (const float*)d_in[2];
    const float* arcStride = (const float*)d_in[3];
    const float* w_ln1     = (const float*)d_in[4];
    const float* w_ln2     = (const float*)d_in[5];
    const float* w_lnf     = (const float*)d_in[6];
    const float* w_qn      = (const float*)d_in[7];
    const float* Wq        = (const float*)d_in[8];
    const float* Wk        = (const float*)d_in[9];
    const float* Wg        = (const float*)d_in[10];
    const float* Wu        = (const float*)d_in[11];
    const float* Wd        = (const float*)d_in[12];
    float* out = (float*)d_out;

    dim3 grid(4096), block(256);
    hipLaunchKernelGGL(adder_model_kernel, grid, block, 0, stream,
                       idx, arcA, arcStart, arcStride,
                       w_ln1, w_ln2, w_lnf, w_qn, Wq, Wk, Wg, Wu, Wd, out);
}

// Round 8
// 109.356 us; speedup vs baseline: 1.4305x; 1.0316x over previous
//
#include <hip/hip_runtime.h>
#include <math.h>

// AdderModel: B=16384 rows, T=64 (== wave), D=3, HD=4, FF=2, VOCAB=10.
// Round 8 = round 4 (last PASSING kernel) + only provably-safe deltas.
// r5-r7 post-mortem: the restructured kernel fails at absmax ~3.6 regardless
// of score precision (r6) or pack flavor (r7) -> structural bug in one of the
// never-hardware-validated pieces (bpermute frags / C-operand mask / shfl
// epilogue / sigma-permuted P). Reverting to the r4 skeleton whose every
// component is validated by a pass. Deltas (each safe given r4's pass):
//  1. half-up 2-op bf16 packs (was 8-op RNE); hi/lo split takes the residual
//     from the ACTUAL packed hi -> split stays exact under any rounding.
//  2. causal-split P (t<32 rows store only s<32, 80 B pitch) + alias P0 over
//     the dead frag buffers and Ol over dead P -> 8.3 KB/wave, 33.4 KB/block,
//     4 blocks/CU (16 waves, was 3/12) with launch_bounds(256,4).
//  3. logits read the table from LDS (uniform b128 broadcast) -> -20 VGPRs.
// Everything else (frag staging through LDS, cndmask-at-exp causal mask,
// natural-s-order P, A=P/B=Vt PV, Ol scatter epilogue) is byte-for-byte r4.

namespace {
constexpr int kVocab = 10;
constexpr float kEps = 1e-6f;
constexpr int kWaves = 4;

typedef __attribute__((ext_vector_type(8)))  short short8;
typedef __attribute__((ext_vector_type(16))) float float16;

// Per-wave LDS layout (bytes). Frag buffers die after the 8 tok_frag reads
// -> P0 aliases them (fence in between). Ol aliases dead P0.
constexpr int kOffQh  = 0;      // uint2[64] bf16x4 q-hi (512 B)
constexpr int kOffQl  = 512;    // q-lo
constexpr int kOffKh  = 1024;   // k-hi
constexpr int kOffKl  = 1536;   // k-lo (frags end at 2048)
constexpr int kOffP0  = 0;      // ALIAS: P rows t=0..31 (s<32 only): 32 x 80 B
constexpr int kOffP1  = 2560;   // P rows t=32..63 (s=0..63): 32 x 144 B
constexpr int kOffVt  = 7168;   // V' rows d=0..4 (+3 pad): 8 x 144 B
constexpr int kOffO   = 0;      // ALIAS: float[5][76] over dead P0 (1520 B)
constexpr int kWaveLds = 8320;  // x4 waves = 33280 B -> 4 blocks/CU
constexpr int kP0P = 40;        // P0 row pitch in shorts (80 B)
constexpr int kP1P = 72;        // P1 row pitch in shorts (144 B)
constexpr int kVtP = 72;        // Vt row pitch in shorts
constexpr int kOP  = 76;        // Ol row pitch in floats

// f32 -> bf16, round-half-up (inputs finite; split residual taken from the
// actual packed hi, so hi/lo stays exact).
__device__ __forceinline__ unsigned bf16_1(float a) {
    return (__float_as_uint(a) + 0x8000u) >> 16;
}
__device__ __forceinline__ unsigned pk_bf16(float a, float b) {
    const unsigned au = __float_as_uint(a) + 0x8000u;
    const unsigned bu = __float_as_uint(b) + 0x8000u;
    return (au >> 16) | (bu & 0xffff0000u);
}
__device__ __forceinline__ float bf_lo(unsigned u) { return __uint_as_float(u << 16); }
__device__ __forceinline__ float bf_hi(unsigned u) { return __uint_as_float(u & 0xffff0000u); }

__device__ __forceinline__ float16 mfma(short8 a, short8 b, float16 c) {
    return __builtin_amdgcn_mfma_f32_32x32x16_bf16(a, b, c, 0, 0, 0);
}

// A/B fragment from a token's packed bf16x4: lanes 0-31 hold {x0..x3,0,0,0,0}
// (k=0..7 half), lanes 32-63 zeros (k=8..15 half).  [r4-validated]
__device__ __forceinline__ short8 tok_frag(const char* wbase, int off, int tok, bool lo_half) {
    uint2 r = *(const uint2*)(wbase + off + tok * 8);
    uint4 t;
    t.x = lo_half ? r.x : 0u;
    t.y = lo_half ? r.y : 0u;
    t.z = 0u; t.w = 0u;
    return __builtin_bit_cast(short8, t);
}

// exp2 a score tile (C layout) and store bf16 into natural s-order row:
// element (reg r, lane h) has s_local = (r&3) + 8*(r>>2) + 4h, stored at
// short offset (8c + 4h + j) from rowbase.  [r4-validated addressing]
template<bool MASKED>
__device__ __forceinline__ void exp_store(const float16& S, ushort* rowbase, int h, int m) {
#pragma unroll
    for (int c = 0; c < 4; ++c) {
        float e[4];
#pragma unroll
        for (int j = 0; j < 4; ++j) {
            float sc = S[4 * c + j];
            if (MASKED) sc = ((j + 8 * c) <= m) ? sc : -INFINITY;  // exp2 -> 0
            e[j] = __builtin_amdgcn_exp2f(sc);
        }
        uint2 w;
        w.x = pk_bf16(e[0], e[1]);
        w.y = pk_bf16(e[2], e[3]);
        *(uint2*)(rowbase + 8 * c + 4 * h) = w;
    }
}

__global__ __launch_bounds__(256, 4) void adder_model_kernel(
    const int* __restrict__ idx,
    const float* __restrict__ p_arcA,
    const float* __restrict__ p_arcStart,
    const float* __restrict__ p_arcStride,
    const float* __restrict__ w_ln1,
    const float* __restrict__ w_ln2,
    const float* __restrict__ w_lnf,
    const float* __restrict__ w_qn,
    const float* __restrict__ Wq,
    const float* __restrict__ Wk,
    const float* __restrict__ Wg,
    const float* __restrict__ Wu,
    const float* __restrict__ Wd,
    float* __restrict__ out)
{
    __shared__ __align__(16) char smem[kWaves][kWaveLds];
    __shared__ __align__(16) float table_s[kVocab * 2];

    const int lane = threadIdx.x & 63;
    const int wid  = threadIdx.x >> 6;
    char* wbase = &smem[wid][0];

    if (threadIdx.x < kVocab) {
        const float ang = p_arcStart[0] + (float)threadIdx.x * p_arcStride[0];
        const float A = p_arcA[0];
        table_s[2 * threadIdx.x]     = A * __cosf(ang);
        table_s[2 * threadIdx.x + 1] = A * __sinf(ang);
    }
    __syncthreads();

    // Per-token constants
    const float t_f = (float)lane;
    const float pe  = __sinf(t_f * 1e-4f);
    const float c0  = __cosf(t_f);
    const float s0  = __sinf(t_f);
    const float ang1 = t_f * 0.57735026918962576f;
    const float c1  = __cosf(ang1);
    const float s1  = __sinf(ang1);

    // Scalar weight loads (uniform -> SGPR)
    const float wl1_0 = w_ln1[0], wl1_1 = w_ln1[1], wl1_2 = w_ln1[2];
    const float wl2_0 = w_ln2[0], wl2_1 = w_ln2[1], wl2_2 = w_ln2[2];
    const float wlf0 = w_lnf[0], wlf1 = w_lnf[1];
    const float wqn0 = w_qn[0], wqn1 = w_qn[1], wqn2 = w_qn[2], wqn3 = w_qn[3];
    const float Wq00 = Wq[0],  Wq01 = Wq[1],  Wq02 = Wq[2];
    const float Wq10 = Wq[3],  Wq11 = Wq[4],  Wq12 = Wq[5];
    const float Wq20 = Wq[6],  Wq21 = Wq[7],  Wq22 = Wq[8];
    const float Wq30 = Wq[9],  Wq31 = Wq[10], Wq32 = Wq[11];
    const float Wk00 = Wk[0],  Wk01 = Wk[1],  Wk02 = Wk[2];
    const float Wk10 = Wk[3],  Wk11 = Wk[4],  Wk12 = Wk[5];
    const float Wk20 = Wk[6],  Wk21 = Wk[7],  Wk22 = Wk[8];
    const float Wk30 = Wk[9],  Wk31 = Wk[10], Wk32 = Wk[11];
    const float Wg00 = Wg[0],  Wg01 = Wg[1],  Wg02 = Wg[2];
    const float Wg10 = Wg[3],  Wg11 = Wg[4],  Wg12 = Wg[5];
    const float Wu00 = Wu[0],  Wu01 = Wu[1],  Wu02 = Wu[2];
    const float Wu10 = Wu[3],  Wu11 = Wu[4],  Wu12 = Wu[5];
    const float Wd00 = Wd[0],  Wd01 = Wd[1];
    const float Wd10 = Wd[2],  Wd11 = Wd[3];
    const float Wd20 = Wd[4],  Wd21 = Wd[5];

    const int row = (int)blockIdx.x * kWaves + wid;

    const int tix = idx[(size_t)row * 64 + lane];
    const float2 emb = *(const float2*)(table_s + 2 * tix);
    const float x0i = emb.x, x1i = emb.y, x2i = pe;

    // RMSNorm 1 + projections
    const float r1 = __builtin_amdgcn_rsqf((x0i*x0i + x1i*x1i + x2i*x2i) * (1.0f/3.0f) + kEps);
    const float h0 = x0i * r1 * wl1_0;
    const float h1 = x1i * r1 * wl1_1;
    const float h2 = x2i * r1 * wl1_2;

    const float qp0 = h0*Wq00 + h1*Wq01 + h2*Wq02;
    const float qp1 = h0*Wq10 + h1*Wq11 + h2*Wq12;
    const float qp2 = h0*Wq20 + h1*Wq21 + h2*Wq22;
    const float qp3 = h0*Wq30 + h1*Wq31 + h2*Wq32;
    const float v0 = h0*Wk00 + h1*Wk01 + h2*Wk02;
    const float v1 = h0*Wk10 + h1*Wk11 + h2*Wk12;
    const float v2 = h0*Wk20 + h1*Wk21 + h2*Wk22;
    const float v3 = h0*Wk30 + h1*Wk31 + h2*Wk32;

    const float rq = __builtin_amdgcn_rsqf((qp0*qp0 + qp1*qp1 + qp2*qp2 + qp3*qp3) * 0.25f + kEps);
    const float rk = __builtin_amdgcn_rsqf((v0*v0 + v1*v1 + v2*v2 + v3*v3) * 0.25f + kEps);
    const float qn0 = qp0*rq*wqn0, qn1 = qp1*rq*wqn1, qn2 = qp2*rq*wqn2, qn3 = qp3*rq*wqn3;
    const float kn0 = v0*rk*wqn0,  kn1 = v1*rk*wqn1,  kn2 = v2*rk*wqn2,  kn3 = v3*rk*wqn3;

    // RoPE; fold 0.5*log2(e) into q -> scores land in exp2 domain
    constexpr float kQS = 0.72134752044448170f;
    const float q0 = (qn0*c0 - qn1*s0) * kQS;
    const float q1 = (qn0*s0 + qn1*c0) * kQS;
    const float q2 = (qn2*c1 - qn3*s1) * kQS;
    const float q3 = (qn2*s1 + qn3*c1) * kQS;
    const float k0 = kn0*c0 - kn1*s0;
    const float k1 = kn0*s0 + kn1*c0;
    const float k2 = kn2*c1 - kn3*s1;
    const float k3 = kn2*s1 + kn3*c1;

    // hi/lo bf16 split (residual from the ACTUAL packed hi -> exact split)
    uint2 qh, ql, kh, kl;
    qh.x = pk_bf16(q0, q1); qh.y = pk_bf16(q2, q3);
    ql.x = pk_bf16(q0 - bf_lo(qh.x), q1 - bf_hi(qh.x));
    ql.y = pk_bf16(q2 - bf_lo(qh.y), q3 - bf_hi(qh.y));
    kh.x = pk_bf16(k0, k1); kh.y = pk_bf16(k2, k3);
    kl.x = pk_bf16(k0 - bf_lo(kh.x), k1 - bf_hi(kh.x));
    kl.y = pk_bf16(k2 - bf_lo(kh.y), k3 - bf_hi(kh.y));
    *(uint2*)(wbase + kOffQh + lane * 8) = qh;
    *(uint2*)(wbase + kOffQl + lane * 8) = ql;
    *(uint2*)(wbase + kOffKh + lane * 8) = kh;
    *(uint2*)(wbase + kOffKl + lane * 8) = kl;

    // V' rows (d=0..3, ones row d=4), natural s columns (col = lane)
    ushort* Vt = (ushort*)(wbase + kOffVt);
    Vt[0 * kVtP + lane] = (ushort)bf16_1(v0);
    Vt[1 * kVtP + lane] = (ushort)bf16_1(v1);
    Vt[2 * kVtP + lane] = (ushort)bf16_1(v2);
    Vt[3 * kVtP + lane] = (ushort)bf16_1(v3);
    Vt[4 * kVtP + lane] = (ushort)0x3F80;  // bf16 1.0 -> l = sum_s P[t][s]
    __threadfence_block();  // frag/Vt writes -> cross-lane reads

    const int  tloc = lane & 31;
    const bool loh  = lane < 32;
    const int  h    = lane >> 5;
    const int  m    = tloc - 4 * h;   // causal keep: s_local <= m

    // Fragments (token-vector form shared by A and B operands)
    const short8 aKh0 = tok_frag(wbase, kOffKh, tloc,      loh);
    const short8 aKl0 = tok_frag(wbase, kOffKl, tloc,      loh);
    const short8 aKh1 = tok_frag(wbase, kOffKh, tloc + 32, loh);
    const short8 aKl1 = tok_frag(wbase, kOffKl, tloc + 32, loh);
    const short8 bQh0 = tok_frag(wbase, kOffQh, tloc,      loh);
    const short8 bQl0 = tok_frag(wbase, kOffQl, tloc,      loh);
    const short8 bQh1 = tok_frag(wbase, kOffQh, tloc + 32, loh);
    const short8 bQl1 = tok_frag(wbase, kOffQl, tloc + 32, loh);
    __threadfence_block();  // frag reads done BEFORE P0 aliases the buffers

    // S^T tiles = K.Q^T; 3-term hi/lo product (drop lo*lo ~2^-18)
    float16 Z = {0,0,0,0,0,0,0,0,0,0,0,0,0,0,0,0};
    float16 S00 = mfma(aKl0, bQh0, mfma(aKh0, bQl0, mfma(aKh0, bQh0, Z)));
    float16 S01 = mfma(aKl0, bQh1, mfma(aKh0, bQl1, mfma(aKh0, bQh1, Z)));
    float16 S11 = mfma(aKl1, bQh1, mfma(aKh1, bQl1, mfma(aKh1, bQh1, Z)));

    ushort* P0 = (ushort*)(wbase + kOffP0);
    ushort* P1 = (ushort*)(wbase + kOffP1);
    exp_store<true >(S00, P0 + tloc * kP0P,      h, m);  // t<32,  s<32: diag mask
    exp_store<false>(S01, P1 + tloc * kP1P,      h, m);  // t>=32, s<32: kept
    exp_store<true >(S11, P1 + tloc * kP1P + 32, h, m);  // t>=32, s>=32: diag mask
    __threadfence_block();

    // O' = P.V' : A = P rows (m=t), B = Vt (n=d)  [r4-validated]
    short8 vb[4];
#pragma unroll
    for (int kc = 0; kc < 4; ++kc)
        vb[kc] = __builtin_bit_cast(short8,
            *(const uint4*)(Vt + (tloc & 7) * kVtP + 16 * kc + 8 * h));

    float16 acc0 = Z, acc1 = Z;
#pragma unroll
    for (int kc = 0; kc < 2; ++kc) {   // t<32 rows: only s<32 kept
        short8 pa = __builtin_bit_cast(short8,
            *(const uint4*)(P0 + tloc * kP0P + 16 * kc + 8 * h));
        acc0 = mfma(pa, vb[kc], acc0);
    }
#pragma unroll
    for (int kc = 0; kc < 4; ++kc) {
        short8 pa = __builtin_bit_cast(short8,
            *(const uint4*)(P1 + tloc * kP1P + 16 * kc + 8 * h));
        acc1 = mfma(pa, vb[kc], acc1);
    }

    // Scatter O' (cols d=0..4 = o0..o3, l) to Ol[d][t]; C-layout chunks of 4
    // regs are t-contiguous -> b128 stores. Ol aliases dead P0 (data-dep safe:
    // stores depend on accs which depend on the P reads).
    float* Ol = (float*)(wbase + kOffO);
    if (tloc < 5) {
#pragma unroll
        for (int c = 0; c < 4; ++c) {
            float4 w0 = make_float4(acc0[4*c], acc0[4*c+1], acc0[4*c+2], acc0[4*c+3]);
            *(float4*)(Ol + tloc * kOP +      8 * c + 4 * h) = w0;
            float4 w1 = make_float4(acc1[4*c], acc1[4*c+1], acc1[4*c+2], acc1[4*c+3]);
            *(float4*)(Ol + tloc * kOP + 32 + 8 * c + 4 * h) = w1;
        }
    }
    __threadfence_block();

    const float o0r = Ol[0 * kOP + lane];
    const float o1r = Ol[1 * kOP + lane];
    const float o2r = Ol[2 * kOP + lane];
    const float o3r = Ol[3 * kOP + lane];
    const float lr  = Ol[4 * kOP + lane];

    const float invl = __builtin_amdgcn_rcpf(lr);
    const float o0 = o0r * invl, o1 = o1r * invl, o2 = o2r * invl, o3 = o3r * invl;

    // x += o @ Wq
    const float xa0 = x0i + o0*Wq00 + o1*Wq10 + o2*Wq20 + o3*Wq30;
    const float xa1 = x1i + o0*Wq01 + o1*Wq11 + o2*Wq21 + o3*Wq31;
    const float xa2 = x2i + o0*Wq02 + o1*Wq12 + o2*Wq22 + o3*Wq32;

    // MLP with RMSNorm 2
    const float r2 = __builtin_amdgcn_rsqf((xa0*xa0 + xa1*xa1 + xa2*xa2) * (1.0f/3.0f) + kEps);
    const float hh0 = xa0*r2*wl2_0, hh1 = xa1*r2*wl2_1, hh2 = xa2*r2*wl2_2;
    const float g0 = hh0*Wg00 + hh1*Wg01 + hh2*Wg02;
    const float g1 = hh0*Wg10 + hh1*Wg11 + hh2*Wg12;
    const float u0 = hh0*Wu00 + hh1*Wu01 + hh2*Wu02;
    const float u1 = hh0*Wu10 + hh1*Wu11 + hh2*Wu12;
    constexpr float kL2E = 1.4426950408889634f;
    const float f0 = g0 * __builtin_amdgcn_rcpf(1.0f + __builtin_amdgcn_exp2f(-g0 * kL2E)) * u0;
    const float f1 = g1 * __builtin_amdgcn_rcpf(1.0f + __builtin_amdgcn_exp2f(-g1 * kL2E)) * u1;
    const float xf0 = xa0 + f0*Wd00 + f1*Wd01;
    const float xf1 = xa1 + f0*Wd10 + f1*Wd11;
    const float xf2 = xa2 + f0*Wd20 + f1*Wd21;

    // Final RMSNorm; only comps 0,1 feed the logits
    const float rf = __builtin_amdgcn_rsqf((xf0*xf0 + xf1*xf1 + xf2*xf2) * (1.0f/3.0f) + kEps);
    const float y0 = xf0 * rf * wlf0;
    const float y1 = xf1 * rf * wlf1;

    // Logits from the LDS table (uniform b128 broadcast reads)
    const float4* tb4 = (const float4*)table_s;
    const float4 T0 = tb4[0], T1 = tb4[1], T2 = tb4[2], T3 = tb4[3], T4 = tb4[4];

    float2* op = (float2*)(out + (size_t)(row * 64 + lane) * kVocab);
    op[0] = float2{y0*T0.x + y1*T0.y, y0*T0.z + y1*T0.w};
    op[1] = float2{y0*T1.x + y1*T1.y, y0*T1.z + y1*T1.w};
    op[2] = float2{y0*T2.x + y1*T2.y, y0*T2.z + y1*T2.w};
    op[3] = float2{y0*T3.x + y1*T3.y, y0*T3.z + y1*T3.w};
    op[4] = float2{y0*T4.x + y1*T4.y, y0*T4.z + y1*T4.w};
}
}  // namespace

extern "C" void kernel_launch(void* const* d_in, const int* in_sizes, int n_in,
                              void* d_out, int out_size, void* d_ws, size_t ws_size,
                              hipStream_t stream) {
    (void)in_sizes; (void)n_in; (void)d_ws; (void)ws_size; (void)out_size;
    const int*   idx       = (const int*)  d_in[0];
    const float* arcA      = (const float*)d_in[1];
    const float* arcStart  = (const float*)d_in[2];
    const float* arcStride = (const float*)d_in[3];
    const float* w_ln1     = (const float*)d_in[4];
    const float* w_ln2     = (const float*)d_in[5];
    const float* w_lnf     = (const float*)d_in[6];
    const float* w_qn      = (const float*)d_in[7];
    const float* Wq        = (const float*)d_in[8];
    const float* Wk        = (const float*)d_in[9];
    const float* Wg        = (const float*)d_in[10];
    const float* Wu        = (const float*)d_in[11];
    const float* Wd        = (const float*)d_in[12];
    float* out = (float*)d_out;

    dim3 grid(4096), block(256);   // 16384 waves = 1 row/wave, exact cover
    hipLaunchKernelGGL(adder_model_kernel, grid, block, 0, stream,
                       idx, arcA, arcStart, arcStride,
                       w_ln1, w_ln2, w_lnf, w_qn, Wq, Wk, Wg, Wu, Wd, out);
}

// Round 9
// 106.317 us; speedup vs baseline: 1.4714x; 1.0286x over previous
//
#include <hip/hip_runtime.h>
#include <math.h>

// AdderModel: B=16384 rows, T=64 (== wave), D=3, HD=4, FF=2, VOCAB=10.
// Round 9 = round 8 (passing) + ONE new concept: P never touches LDS.
// After S^T = K.Q^T, lane (tloc,h) already holds row t=tloc of P (16 regs,
// s = (r&3)+8*(r>>2)+4h). Define the PV k->s mapping per 16-chunk as
// [0,1,2,3,8,9,10,11 | 4,5,6,7,12,15,...]: then the packed exp registers ARE
// the A-operand (m=t) verbatim. The matching B re-index is absorbed into V's
// LDS column: vcol = swap(bit2,bit3)(s). MFMA sums over k, so equal
// re-indexing of A and B k is exact. Removes 12 b64 P-stores + 6 b128
// P-reads + 2 fences (r8's LDS-pipe model: ~12.5 us of ~30.5 was DS ops).
// Unchanged from r8 (validated): frag staging via LDS, cndmask-at-exp causal
// mask, half-up packs with exact hi/lo split, Vt read pattern 16c+8h,
// Ol scatter epilogue, LDS-table logits.

namespace {
constexpr int kVocab = 10;
constexpr float kEps = 1e-6f;
constexpr int kWaves = 4;

typedef __attribute__((ext_vector_type(8)))  short short8;
typedef __attribute__((ext_vector_type(16))) float float16;

// Per-wave LDS layout (bytes). No aliasing needed anymore.
constexpr int kOffQh  = 0;      // uint2[64] bf16x4 q-hi (512 B)
constexpr int kOffQl  = 512;    // q-lo
constexpr int kOffKh  = 1024;   // k-hi
constexpr int kOffKl  = 1536;   // k-lo (frags end at 2048)
constexpr int kOffVt  = 2048;   // V' rows d=0..4 (+3 pad): 8 x 144 B
constexpr int kOffO   = 3200;   // float[5][76] (1520 B)
constexpr int kWaveLds = 4736;  // x4 waves = 18944 B/block
constexpr int kVtP = 72;        // Vt row pitch in shorts
constexpr int kOP  = 76;        // Ol row pitch in floats

// f32 -> bf16, round-half-up (inputs finite; hi/lo split residual is taken
// from the ACTUAL packed hi, so the split stays exact).
__device__ __forceinline__ unsigned bf16_1(float a) {
    return (__float_as_uint(a) + 0x8000u) >> 16;
}
__device__ __forceinline__ unsigned pk_bf16(float a, float b) {
    const unsigned au = __float_as_uint(a) + 0x8000u;
    const unsigned bu = __float_as_uint(b) + 0x8000u;
    return (au >> 16) | (bu & 0xffff0000u);
}
__device__ __forceinline__ float bf_lo(unsigned u) { return __uint_as_float(u << 16); }
__device__ __forceinline__ float bf_hi(unsigned u) { return __uint_as_float(u & 0xffff0000u); }

__device__ __forceinline__ float16 mfma(short8 a, short8 b, float16 c) {
    return __builtin_amdgcn_mfma_f32_32x32x16_bf16(a, b, c, 0, 0, 0);
}

// A/B fragment from a token's packed bf16x4: lanes 0-31 hold {x0..x3,0,0,0,0}
// (k=0..7 half), lanes 32-63 zeros (k=8..15 half).  [r8-validated]
__device__ __forceinline__ short8 tok_frag(const char* wbase, int off, int tok, bool lo_half) {
    uint2 r = *(const uint2*)(wbase + off + tok * 8);
    uint4 t;
    t.x = lo_half ? r.x : 0u;
    t.y = lo_half ? r.y : 0u;
    t.z = 0u; t.w = 0u;
    return __builtin_bit_cast(short8, t);
}

// exp2 + pack a score tile IN REGISTER ORDER: out[i] = pk(e[2i], e[2i+1]).
// Causal mask (r8-validated mapping): reg r has s_local = (r&3)+8*(r>>2)+4h,
// keep iff ((r&3)+8*(r>>2)) <= m where m = tloc-4h.
template<bool MASKED>
__device__ __forceinline__ void exp_pack(const float16& S, unsigned* out, int m) {
#pragma unroll
    for (int i = 0; i < 8; ++i) {
        const int r0 = 2 * i, r1 = 2 * i + 1;
        float sa = S[r0], sb = S[r1];
        if (MASKED) {
            sa = (((r0 & 3) + 8 * (r0 >> 2)) <= m) ? sa : -INFINITY;  // exp2 -> 0
            sb = (((r1 & 3) + 8 * (r1 >> 2)) <= m) ? sb : -INFINITY;
        }
        out[i] = pk_bf16(__builtin_amdgcn_exp2f(sa), __builtin_amdgcn_exp2f(sb));
    }
}

// A-operand chunk straight from 4 packed uints (8 bf16).
__device__ __forceinline__ short8 af(const unsigned* p) {
    uint4 t;
    t.x = p[0]; t.y = p[1]; t.z = p[2]; t.w = p[3];
    return __builtin_bit_cast(short8, t);
}
__device__ __forceinline__ short8 ld8(const void* p) {
    return __builtin_bit_cast(short8, *(const uint4*)p);
}

__global__ __launch_bounds__(256, 4) void adder_model_kernel(
    const int* __restrict__ idx,
    const float* __restrict__ p_arcA,
    const float* __restrict__ p_arcStart,
    const float* __restrict__ p_arcStride,
    const float* __restrict__ w_ln1,
    const float* __restrict__ w_ln2,
    const float* __restrict__ w_lnf,
    const float* __restrict__ w_qn,
    const float* __restrict__ Wq,
    const float* __restrict__ Wk,
    const float* __restrict__ Wg,
    const float* __restrict__ Wu,
    const float* __restrict__ Wd,
    float* __restrict__ out)
{
    __shared__ __align__(16) char smem[kWaves][kWaveLds];
    __shared__ __align__(16) float table_s[kVocab * 2];

    const int lane = threadIdx.x & 63;
    const int wid  = threadIdx.x >> 6;
    char* wbase = &smem[wid][0];

    if (threadIdx.x < kVocab) {
        const float ang = p_arcStart[0] + (float)threadIdx.x * p_arcStride[0];
        const float A = p_arcA[0];
        table_s[2 * threadIdx.x]     = A * __cosf(ang);
        table_s[2 * threadIdx.x + 1] = A * __sinf(ang);
    }
    __syncthreads();

    // Per-token constants
    const float t_f = (float)lane;
    const float pe  = __sinf(t_f * 1e-4f);
    const float c0  = __cosf(t_f);
    const float s0  = __sinf(t_f);
    const float ang1 = t_f * 0.57735026918962576f;
    const float c1  = __cosf(ang1);
    const float s1  = __sinf(ang1);

    // Scalar weight loads (uniform -> SGPR)
    const float wl1_0 = w_ln1[0], wl1_1 = w_ln1[1], wl1_2 = w_ln1[2];
    const float wl2_0 = w_ln2[0], wl2_1 = w_ln2[1], wl2_2 = w_ln2[2];
    const float wlf0 = w_lnf[0], wlf1 = w_lnf[1];
    const float wqn0 = w_qn[0], wqn1 = w_qn[1], wqn2 = w_qn[2], wqn3 = w_qn[3];
    const float Wq00 = Wq[0],  Wq01 = Wq[1],  Wq02 = Wq[2];
    const float Wq10 = Wq[3],  Wq11 = Wq[4],  Wq12 = Wq[5];
    const float Wq20 = Wq[6],  Wq21 = Wq[7],  Wq22 = Wq[8];
    const float Wq30 = Wq[9],  Wq31 = Wq[10], Wq32 = Wq[11];
    const float Wk00 = Wk[0],  Wk01 = Wk[1],  Wk02 = Wk[2];
    const float Wk10 = Wk[3],  Wk11 = Wk[4],  Wk12 = Wk[5];
    const float Wk20 = Wk[6],  Wk21 = Wk[7],  Wk22 = Wk[8];
    const float Wk30 = Wk[9],  Wk31 = Wk[10], Wk32 = Wk[11];
    const float Wg00 = Wg[0],  Wg01 = Wg[1],  Wg02 = Wg[2];
    const float Wg10 = Wg[3],  Wg11 = Wg[4],  Wg12 = Wg[5];
    const float Wu00 = Wu[0],  Wu01 = Wu[1],  Wu02 = Wu[2];
    const float Wu10 = Wu[3],  Wu11 = Wu[4],  Wu12 = Wu[5];
    const float Wd00 = Wd[0],  Wd01 = Wd[1];
    const float Wd10 = Wd[2],  Wd11 = Wd[3];
    const float Wd20 = Wd[4],  Wd21 = Wd[5];

    const int row = (int)blockIdx.x * kWaves + wid;

    const int tix = idx[(size_t)row * 64 + lane];
    const float2 emb = *(const float2*)(table_s + 2 * tix);
    const float x0i = emb.x, x1i = emb.y, x2i = pe;

    // RMSNorm 1 + projections
    const float r1 = __builtin_amdgcn_rsqf((x0i*x0i + x1i*x1i + x2i*x2i) * (1.0f/3.0f) + kEps);
    const float h0 = x0i * r1 * wl1_0;
    const float h1 = x1i * r1 * wl1_1;
    const float h2 = x2i * r1 * wl1_2;

    const float qp0 = h0*Wq00 + h1*Wq01 + h2*Wq02;
    const float qp1 = h0*Wq10 + h1*Wq11 + h2*Wq12;
    const float qp2 = h0*Wq20 + h1*Wq21 + h2*Wq22;
    const float qp3 = h0*Wq30 + h1*Wq31 + h2*Wq32;
    const float v0 = h0*Wk00 + h1*Wk01 + h2*Wk02;
    const float v1 = h0*Wk10 + h1*Wk11 + h2*Wk12;
    const float v2 = h0*Wk20 + h1*Wk21 + h2*Wk22;
    const float v3 = h0*Wk30 + h1*Wk31 + h2*Wk32;

    const float rq = __builtin_amdgcn_rsqf((qp0*qp0 + qp1*qp1 + qp2*qp2 + qp3*qp3) * 0.25f + kEps);
    const float rk = __builtin_amdgcn_rsqf((v0*v0 + v1*v1 + v2*v2 + v3*v3) * 0.25f + kEps);
    const float qn0 = qp0*rq*wqn0, qn1 = qp1*rq*wqn1, qn2 = qp2*rq*wqn2, qn3 = qp3*rq*wqn3;
    const float kn0 = v0*rk*wqn0,  kn1 = v1*rk*wqn1,  kn2 = v2*rk*wqn2,  kn3 = v3*rk*wqn3;

    // RoPE; fold 0.5*log2(e) into q -> scores land in exp2 domain
    constexpr float kQS = 0.72134752044448170f;
    const float q0 = (qn0*c0 - qn1*s0) * kQS;
    const float q1 = (qn0*s0 + qn1*c0) * kQS;
    const float q2 = (qn2*c1 - qn3*s1) * kQS;
    const float q3 = (qn2*s1 + qn3*c1) * kQS;
    const float k0 = kn0*c0 - kn1*s0;
    const float k1 = kn0*s0 + kn1*c0;
    const float k2 = kn2*c1 - kn3*s1;
    const float k3 = kn2*s1 + kn3*c1;

    // hi/lo bf16 split (residual from the ACTUAL packed hi -> exact split)
    uint2 qh, ql, kh, kl;
    qh.x = pk_bf16(q0, q1); qh.y = pk_bf16(q2, q3);
    ql.x = pk_bf16(q0 - bf_lo(qh.x), q1 - bf_hi(qh.x));
    ql.y = pk_bf16(q2 - bf_lo(qh.y), q3 - bf_hi(qh.y));
    kh.x = pk_bf16(k0, k1); kh.y = pk_bf16(k2, k3);
    kl.x = pk_bf16(k0 - bf_lo(kh.x), k1 - bf_hi(kh.x));
    kl.y = pk_bf16(k2 - bf_lo(kh.y), k3 - bf_hi(kh.y));
    *(uint2*)(wbase + kOffQh + lane * 8) = qh;
    *(uint2*)(wbase + kOffQl + lane * 8) = ql;
    *(uint2*)(wbase + kOffKh + lane * 8) = kh;
    *(uint2*)(wbase + kOffKl + lane * 8) = kl;

    // V' rows (d=0..3, ones row d=4) at k-position columns:
    // vcol(s) = swap(bit2,bit3)(s) so B's k-order matches the A-from-register
    // k->s mapping [0,1,2,3,8,9,10,11 | 4,5,6,7,12,13,14,15] per 16-chunk.
    ushort* Vt = (ushort*)(wbase + kOffVt);
    const int vcol = (lane & ~12) | ((lane & 4) << 1) | ((lane & 8) >> 1);
    Vt[0 * kVtP + vcol] = (ushort)bf16_1(v0);
    Vt[1 * kVtP + vcol] = (ushort)bf16_1(v1);
    Vt[2 * kVtP + vcol] = (ushort)bf16_1(v2);
    Vt[3 * kVtP + vcol] = (ushort)bf16_1(v3);
    Vt[4 * kVtP + vcol] = (ushort)0x3F80;  // bf16 1.0 -> l = sum_s P[t][s]
    __threadfence_block();  // all LDS writes -> cross-lane reads below

    const int  tloc = lane & 31;
    const bool loh  = lane < 32;
    const int  h    = lane >> 5;
    const int  m    = tloc - 4 * h;   // causal keep: s_local <= m

    // Fragments (token-vector form shared by A and B operands) [r8-validated]
    const short8 aKh0 = tok_frag(wbase, kOffKh, tloc,      loh);
    const short8 aKl0 = tok_frag(wbase, kOffKl, tloc,      loh);
    const short8 aKh1 = tok_frag(wbase, kOffKh, tloc + 32, loh);
    const short8 aKl1 = tok_frag(wbase, kOffKl, tloc + 32, loh);
    const short8 bQh0 = tok_frag(wbase, kOffQh, tloc,      loh);
    const short8 bQl0 = tok_frag(wbase, kOffQl, tloc,      loh);
    const short8 bQh1 = tok_frag(wbase, kOffQh, tloc + 32, loh);
    const short8 bQl1 = tok_frag(wbase, kOffQl, tloc + 32, loh);

    // B-frags for PV (chunk c covers Vt cols 16c..16c+15) [r8 read pattern]
    short8 vb[4];
#pragma unroll
    for (int kc = 0; kc < 4; ++kc)
        vb[kc] = ld8(Vt + (tloc & 7) * kVtP + 16 * kc + 8 * h);

    // S^T tiles = K.Q^T; 3-term hi/lo product (drop lo*lo ~2^-18)
    float16 Z = {0,0,0,0,0,0,0,0,0,0,0,0,0,0,0,0};
    float16 S00 = mfma(aKl0, bQh0, mfma(aKh0, bQl0, mfma(aKh0, bQh0, Z)));
    float16 S01 = mfma(aKl0, bQh1, mfma(aKh0, bQl1, mfma(aKh0, bQh1, Z)));
    float16 S11 = mfma(aKl1, bQh1, mfma(aKh1, bQl1, mfma(aKh1, bQh1, Z)));

    // exp2 + pack in register order; packed regs ARE the PV A-operand.
    unsigned p00[8], p01[8], p11[8];
    exp_pack<true >(S00, p00, m);  // t<32,  s<32: diag mask
    exp_pack<false>(S01, p01, m);  // t>=32, s<32: fully kept
    exp_pack<true >(S11, p11, m);  // t>=32, s>=32: diag mask

    // O' = P.V' : A = P (m=t) straight from regs, B = vb (n=d)
    float16 acc0 = mfma(af(p00 + 4), vb[1], mfma(af(p00), vb[0], Z));
    float16 acc1 = mfma(af(p11 + 4), vb[3],
                   mfma(af(p11),     vb[2],
                   mfma(af(p01 + 4), vb[1],
                   mfma(af(p01),     vb[0], Z))));

    // Scatter O' (cols d=0..4 = o0..o3, l) to Ol[d][t]; C-layout chunks of 4
    // regs are t-contiguous -> b128 stores.  [r8-validated]
    float* Ol = (float*)(wbase + kOffO);
    if (tloc < 5) {
#pragma unroll
        for (int c = 0; c < 4; ++c) {
            float4 w0 = make_float4(acc0[4*c], acc0[4*c+1], acc0[4*c+2], acc0[4*c+3]);
            *(float4*)(Ol + tloc * kOP +      8 * c + 4 * h) = w0;
            float4 w1 = make_float4(acc1[4*c], acc1[4*c+1], acc1[4*c+2], acc1[4*c+3]);
            *(float4*)(Ol + tloc * kOP + 32 + 8 * c + 4 * h) = w1;
        }
    }
    __threadfence_block();

    const float o0r = Ol[0 * kOP + lane];
    const float o1r = Ol[1 * kOP + lane];
    const float o2r = Ol[2 * kOP + lane];
    const float o3r = Ol[3 * kOP + lane];
    const float lr  = Ol[4 * kOP + lane];

    const float invl = __builtin_amdgcn_rcpf(lr);
    const float o0 = o0r * invl, o1 = o1r * invl, o2 = o2r * invl, o3 = o3r * invl;

    // x += o @ Wq
    const float xa0 = x0i + o0*Wq00 + o1*Wq10 + o2*Wq20 + o3*Wq30;
    const float xa1 = x1i + o0*Wq01 + o1*Wq11 + o2*Wq21 + o3*Wq31;
    const float xa2 = x2i + o0*Wq02 + o1*Wq12 + o2*Wq22 + o3*Wq32;

    // MLP with RMSNorm 2
    const float r2 = __builtin_amdgcn_rsqf((xa0*xa0 + xa1*xa1 + xa2*xa2) * (1.0f/3.0f) + kEps);
    const float hh0 = xa0*r2*wl2_0, hh1 = xa1*r2*wl2_1, hh2 = xa2*r2*wl2_2;
    const float g0 = hh0*Wg00 + hh1*Wg01 + hh2*Wg02;
    const float g1 = hh0*Wg10 + hh1*Wg11 + hh2*Wg12;
    const float u0 = hh0*Wu00 + hh1*Wu01 + hh2*Wu02;
    const float u1 = hh0*Wu10 + hh1*Wu11 + hh2*Wu12;
    constexpr float kL2E = 1.4426950408889634f;
    const float f0 = g0 * __builtin_amdgcn_rcpf(1.0f + __builtin_amdgcn_exp2f(-g0 * kL2E)) * u0;
    const float f1 = g1 * __builtin_amdgcn_rcpf(1.0f + __builtin_amdgcn_exp2f(-g1 * kL2E)) * u1;
    const float xf0 = xa0 + f0*Wd00 + f1*Wd01;
    const float xf1 = xa1 + f0*Wd10 + f1*Wd11;
    const float xf2 = xa2 + f0*Wd20 + f1*Wd21;

    // Final RMSNorm; only comps 0,1 feed the logits
    const float rf = __builtin_amdgcn_rsqf((xf0*xf0 + xf1*xf1 + xf2*xf2) * (1.0f/3.0f) + kEps);
    const float y0 = xf0 * rf * wlf0;
    const float y1 = xf1 * rf * wlf1;

    // Logits from the LDS table (uniform b128 broadcast reads)
    const float4* tb4 = (const float4*)table_s;
    const float4 T0 = tb4[0], T1 = tb4[1], T2 = tb4[2], T3 = tb4[3], T4 = tb4[4];

    float2* op = (float2*)(out + (size_t)(row * 64 + lane) * kVocab);
    op[0] = float2{y0*T0.x + y1*T0.y, y0*T0.z + y1*T0.w};
    op[1] = float2{y0*T1.x + y1*T1.y, y0*T1.z + y1*T1.w};
    op[2] = float2{y0*T2.x + y1*T2.y, y0*T2.z + y1*T2.w};
    op[3] = float2{y0*T3.x + y1*T3.y, y0*T3.z + y1*T3.w};
    op[4] = float2{y0*T4.x + y1*T4.y, y0*T4.z + y1*T4.w};
}
}  // namespace

extern "C" void kernel_launch(void* const* d_in, const int* in_sizes, int n_in,
                              void* d_out, int out_size, void* d_ws, size_t ws_size,
                              hipStream_t stream) {
    (void)in_sizes; (void)n_in; (void)d_ws; (void)ws_size; (void)out_size;
    const int*   idx       = (const int*)  d_in[0];
    const float* arcA      = (const float*)d_in[1];
    const float* arcStart  = (const float*)d_in[2];
    const float* arcStride = (const float*)d_in[3];
    const float* w_ln1     = (const float*)d_in[4];
    const float* w_ln2     = (const float*)d_in[5];
    const float* w_lnf     = (const float*)d_in[6];
    const float* w_qn      = (const float*)d_in[7];
    const float* Wq        = (const float*)d_in[8];
    const float* Wk        = (const float*)d_in[9];
    const float* Wg        = (const float*)d_in[10];
    const float* Wu        = (const float*)d_in[11];
    const float* Wd        = (const float*)d_in[12];
    float* out = (float*)d_out;

    dim3 grid(4096), block(256);   // 16384 waves = 1 row/wave, exact cover
    hipLaunchKernelGGL(adder_model_kernel, grid, block, 0, stream,
                       idx, arcA, arcStart, arcStride,
                       w_ln1, w_ln2, w_lnf, w_qn, Wq, Wk, Wg, Wu, Wd, out);
}

// Round 10
// 106.152 us; speedup vs baseline: 1.4737x; 1.0016x over previous
//
#include <hip/hip_runtime.h>
#include <math.h>

// AdderModel: B=16384 rows, T=64 (== wave), D=3, HD=4, FF=2, VOCAB=10.
// Round 10 = round 9 (passing, ~27.5 us) minus the two LDS fence round-trips.
// r9 pipe model: no pipe >31% busy at 4 waves/SIMD -> latency-bound on the
// serial chain; the two fence round-trips (frag staging, Ol scatter) move
// tiny half-wave payloads. Changes (each argued from r9-validated algebra):
//  1. tile-0 frags straight from own registers (lane<32 reads its own token;
//     lane>=32 is zeroed by the select) - values bit-identical to r9.
//  2. tile-1 frags via __shfl_xor(x,32,64) of qh/ql/kh/kl - kills the frag
//     LDS buffers and fence #1.
//  3. PV operand swap: A=vb (V', m=d), B=packed P regs (n=t). Same k-slot
//     mapping on both sides (swap23 algebra), same chunk pairing -> D[d][t]
//     token-per-lane; epilogue = 4 shfl_xor + selects. Kills Ol + fence #2.
//     Vt pad rows (5..7) zeroed so the A-operand junk rows are defined.
//  4. LDS = Vt only (1152 B/wave). One fence remains (Vt write -> vb read).
// Unchanged: hi/lo fp32-accurate scores, cndmask-at-exp causal mask, half-up
// packs with exact split, register-order P + swap23 vcol, LDS-table logits.

namespace {
constexpr int kVocab = 10;
constexpr float kEps = 1e-6f;
constexpr int kWaves = 4;

typedef __attribute__((ext_vector_type(8)))  short short8;
typedef __attribute__((ext_vector_type(16))) float float16;

constexpr int kVtP = 72;          // Vt row pitch in shorts (144 B)
constexpr int kWaveLds = 1152;    // 8 rows x 144 B

// f32 -> bf16, round-half-up (inputs finite; hi/lo split residual is taken
// from the ACTUAL packed hi, so the split stays exact).
__device__ __forceinline__ unsigned bf16_1(float a) {
    return (__float_as_uint(a) + 0x8000u) >> 16;
}
__device__ __forceinline__ unsigned pk_bf16(float a, float b) {
    const unsigned au = __float_as_uint(a) + 0x8000u;
    const unsigned bu = __float_as_uint(b) + 0x8000u;
    return (au >> 16) | (bu & 0xffff0000u);
}
__device__ __forceinline__ float bf_lo(unsigned u) { return __uint_as_float(u << 16); }
__device__ __forceinline__ float bf_hi(unsigned u) { return __uint_as_float(u & 0xffff0000u); }

__device__ __forceinline__ float16 mfma(short8 a, short8 b, float16 c) {
    return __builtin_amdgcn_mfma_f32_32x32x16_bf16(a, b, c, 0, 0, 0);
}
__device__ __forceinline__ unsigned shflx32(unsigned x) {
    return (unsigned)__shfl_xor((int)x, 32, 64);
}

// Frag from a packed bf16x4: k-slots 0..3 hold {x0..x3} on lanes<32 (k=0..7
// half), zeros on lanes>=32 (k=8..15 half).  [r8/r9-validated form]
__device__ __forceinline__ short8 mk_frag(uint2 v, bool lo) {
    uint4 t;
    t.x = lo ? v.x : 0u;
    t.y = lo ? v.y : 0u;
    t.z = 0u; t.w = 0u;
    return __builtin_bit_cast(short8, t);
}
__device__ __forceinline__ short8 ld8(const void* p) {
    return __builtin_bit_cast(short8, *(const uint4*)p);
}

// exp2 + pack a score tile IN REGISTER ORDER: out[i] = pk(e[2i], e[2i+1]).
// Causal mask (validated): reg r has s_local = (r&3)+8*(r>>2)+4h, keep iff
// ((r&3)+8*(r>>2)) <= m where m = tloc-4h.
template<bool MASKED>
__device__ __forceinline__ void exp_pack(const float16& S, unsigned* out, int m) {
#pragma unroll
    for (int i = 0; i < 8; ++i) {
        const int r0 = 2 * i, r1 = 2 * i + 1;
        float sa = S[r0], sb = S[r1];
        if (MASKED) {
            sa = (((r0 & 3) + 8 * (r0 >> 2)) <= m) ? sa : -INFINITY;  // exp2 -> 0
            sb = (((r1 & 3) + 8 * (r1 >> 2)) <= m) ? sb : -INFINITY;
        }
        out[i] = pk_bf16(__builtin_amdgcn_exp2f(sa), __builtin_amdgcn_exp2f(sb));
    }
}

// Operand chunk straight from 4 packed uints (8 bf16).
__device__ __forceinline__ short8 af(const unsigned* p) {
    uint4 t;
    t.x = p[0]; t.y = p[1]; t.z = p[2]; t.w = p[3];
    return __builtin_bit_cast(short8, t);
}

__global__ __launch_bounds__(256, 4) void adder_model_kernel(
    const int* __restrict__ idx,
    const float* __restrict__ p_arcA,
    const float* __restrict__ p_arcStart,
    const float* __restrict__ p_arcStride,
    const float* __restrict__ w_ln1,
    const float* __restrict__ w_ln2,
    const float* __restrict__ w_lnf,
    const float* __restrict__ w_qn,
    const float* __restrict__ Wq,
    const float* __restrict__ Wk,
    const float* __restrict__ Wg,
    const float* __restrict__ Wu,
    const float* __restrict__ Wd,
    float* __restrict__ out)
{
    __shared__ __align__(16) char smem[kWaves][kWaveLds];
    __shared__ __align__(16) float table_s[kVocab * 2];

    const int lane = threadIdx.x & 63;
    const int wid  = threadIdx.x >> 6;
    ushort* Vt = (ushort*)&smem[wid][0];

    if (threadIdx.x < kVocab) {
        const float ang = p_arcStart[0] + (float)threadIdx.x * p_arcStride[0];
        const float A = p_arcA[0];
        table_s[2 * threadIdx.x]     = A * __cosf(ang);
        table_s[2 * threadIdx.x + 1] = A * __sinf(ang);
    }
    __syncthreads();

    // Per-token constants
    const float t_f = (float)lane;
    const float pe  = __sinf(t_f * 1e-4f);
    const float c0  = __cosf(t_f);
    const float s0  = __sinf(t_f);
    const float ang1 = t_f * 0.57735026918962576f;
    const float c1  = __cosf(ang1);
    const float s1  = __sinf(ang1);

    // Scalar weight loads (uniform -> SGPR)
    const float wl1_0 = w_ln1[0], wl1_1 = w_ln1[1], wl1_2 = w_ln1[2];
    const float wl2_0 = w_ln2[0], wl2_1 = w_ln2[1], wl2_2 = w_ln2[2];
    const float wlf0 = w_lnf[0], wlf1 = w_lnf[1];
    const float wqn0 = w_qn[0], wqn1 = w_qn[1], wqn2 = w_qn[2], wqn3 = w_qn[3];
    const float Wq00 = Wq[0],  Wq01 = Wq[1],  Wq02 = Wq[2];
    const float Wq10 = Wq[3],  Wq11 = Wq[4],  Wq12 = Wq[5];
    const float Wq20 = Wq[6],  Wq21 = Wq[7],  Wq22 = Wq[8];
    const float Wq30 = Wq[9],  Wq31 = Wq[10], Wq32 = Wq[11];
    const float Wk00 = Wk[0],  Wk01 = Wk[1],  Wk02 = Wk[2];
    const float Wk10 = Wk[3],  Wk11 = Wk[4],  Wk12 = Wk[5];
    const float Wk20 = Wk[6],  Wk21 = Wk[7],  Wk22 = Wk[8];
    const float Wk30 = Wk[9],  Wk31 = Wk[10], Wk32 = Wk[11];
    const float Wg00 = Wg[0],  Wg01 = Wg[1],  Wg02 = Wg[2];
    const float Wg10 = Wg[3],  Wg11 = Wg[4],  Wg12 = Wg[5];
    const float Wu00 = Wu[0],  Wu01 = Wu[1],  Wu02 = Wu[2];
    const float Wu10 = Wu[3],  Wu11 = Wu[4],  Wu12 = Wu[5];
    const float Wd00 = Wd[0],  Wd01 = Wd[1];
    const float Wd10 = Wd[2],  Wd11 = Wd[3];
    const float Wd20 = Wd[4],  Wd21 = Wd[5];

    const int row = (int)blockIdx.x * kWaves + wid;

    const int tix = idx[(size_t)row * 64 + lane];
    const float2 emb = *(const float2*)(table_s + 2 * tix);
    const float x0i = emb.x, x1i = emb.y, x2i = pe;

    // RMSNorm 1 + projections
    const float r1 = __builtin_amdgcn_rsqf((x0i*x0i + x1i*x1i + x2i*x2i) * (1.0f/3.0f) + kEps);
    const float h0 = x0i * r1 * wl1_0;
    const float h1 = x1i * r1 * wl1_1;
    const float h2 = x2i * r1 * wl1_2;

    const float qp0 = h0*Wq00 + h1*Wq01 + h2*Wq02;
    const float qp1 = h0*Wq10 + h1*Wq11 + h2*Wq12;
    const float qp2 = h0*Wq20 + h1*Wq21 + h2*Wq22;
    const float qp3 = h0*Wq30 + h1*Wq31 + h2*Wq32;
    const float v0 = h0*Wk00 + h1*Wk01 + h2*Wk02;
    const float v1 = h0*Wk10 + h1*Wk11 + h2*Wk12;
    const float v2 = h0*Wk20 + h1*Wk21 + h2*Wk22;
    const float v3 = h0*Wk30 + h1*Wk31 + h2*Wk32;

    const float rq = __builtin_amdgcn_rsqf((qp0*qp0 + qp1*qp1 + qp2*qp2 + qp3*qp3) * 0.25f + kEps);
    const float rk = __builtin_amdgcn_rsqf((v0*v0 + v1*v1 + v2*v2 + v3*v3) * 0.25f + kEps);
    const float qn0 = qp0*rq*wqn0, qn1 = qp1*rq*wqn1, qn2 = qp2*rq*wqn2, qn3 = qp3*rq*wqn3;
    const float kn0 = v0*rk*wqn0,  kn1 = v1*rk*wqn1,  kn2 = v2*rk*wqn2,  kn3 = v3*rk*wqn3;

    // RoPE; fold 0.5*log2(e) into q -> scores land in exp2 domain
    constexpr float kQS = 0.72134752044448170f;
    const float q0 = (qn0*c0 - qn1*s0) * kQS;
    const float q1 = (qn0*s0 + qn1*c0) * kQS;
    const float q2 = (qn2*c1 - qn3*s1) * kQS;
    const float q3 = (qn2*s1 + qn3*c1) * kQS;
    const float k0 = kn0*c0 - kn1*s0;
    const float k1 = kn0*s0 + kn1*c0;
    const float k2 = kn2*c1 - kn3*s1;
    const float k3 = kn2*s1 + kn3*c1;

    // hi/lo bf16 split (residual from the ACTUAL packed hi -> exact split)
    uint2 qh, ql, kh, kl;
    qh.x = pk_bf16(q0, q1); qh.y = pk_bf16(q2, q3);
    ql.x = pk_bf16(q0 - bf_lo(qh.x), q1 - bf_hi(qh.x));
    ql.y = pk_bf16(q2 - bf_lo(qh.y), q3 - bf_hi(qh.y));
    kh.x = pk_bf16(k0, k1); kh.y = pk_bf16(k2, k3);
    kl.x = pk_bf16(k0 - bf_lo(kh.x), k1 - bf_hi(kh.x));
    kl.y = pk_bf16(k2 - bf_lo(kh.y), k3 - bf_hi(kh.y));

    // V' rows (d=0..3, ones row d=4, zero pad rows 5..7) at swap23 columns:
    // vcol(s) = swap(bit2,bit3)(s) matches the register k->s mapping
    // [0,1,2,3,8,9,10,11 | 4,5,6,7,12,13,14,15] per 16-chunk. [r9-validated]
    const int vcol = (lane & ~12) | ((lane & 4) << 1) | ((lane & 8) >> 1);
    Vt[0 * kVtP + vcol] = (ushort)bf16_1(v0);
    Vt[1 * kVtP + vcol] = (ushort)bf16_1(v1);
    Vt[2 * kVtP + vcol] = (ushort)bf16_1(v2);
    Vt[3 * kVtP + vcol] = (ushort)bf16_1(v3);
    Vt[4 * kVtP + vcol] = (ushort)0x3F80;  // bf16 1.0 -> l = sum_s P[t][s]
    Vt[5 * kVtP + vcol] = 0;               // defined junk for A pad rows
    Vt[6 * kVtP + vcol] = 0;
    Vt[7 * kVtP + vcol] = 0;

    // Tile-1 values: partner half's qh/ql/kh/kl via half-swap (no LDS buffer)
    uint2 qh1, ql1, kh1, kl1;
    qh1.x = shflx32(qh.x); qh1.y = shflx32(qh.y);
    ql1.x = shflx32(ql.x); ql1.y = shflx32(ql.y);
    kh1.x = shflx32(kh.x); kh1.y = shflx32(kh.y);
    kl1.x = shflx32(kl.x); kl1.y = shflx32(kl.y);

    const int  tloc = lane & 31;
    const bool loh  = lane < 32;
    const int  h    = lane >> 5;
    const int  m    = tloc - 4 * h;   // causal keep: s_local <= m

    // Fragments: tile-0 from own registers (lane<32 token == own lane;
    // lane>=32 zeroed by the select anyway). Tile-1 from the half-swap.
    const short8 aKh0 = mk_frag(kh,  loh);
    const short8 aKl0 = mk_frag(kl,  loh);
    const short8 aKh1 = mk_frag(kh1, loh);
    const short8 aKl1 = mk_frag(kl1, loh);
    const short8 bQh0 = mk_frag(qh,  loh);
    const short8 bQl0 = mk_frag(ql,  loh);
    const short8 bQh1 = mk_frag(qh1, loh);
    const short8 bQl1 = mk_frag(ql1, loh);

    __threadfence_block();  // Vt writes -> cross-lane vb reads

    // V' operand chunks (row d = tloc, pad-masked to 8 rows) [r9 read pattern]
    short8 vb[4];
#pragma unroll
    for (int kc = 0; kc < 4; ++kc)
        vb[kc] = ld8(Vt + (tloc & 7) * kVtP + 16 * kc + 8 * h);

    // S^T tiles = K.Q^T; 3-term hi/lo product (drop lo*lo ~2^-18)
    float16 Z = {0,0,0,0,0,0,0,0,0,0,0,0,0,0,0,0};
    float16 S00 = mfma(aKl0, bQh0, mfma(aKh0, bQl0, mfma(aKh0, bQh0, Z)));
    float16 S01 = mfma(aKl0, bQh1, mfma(aKh0, bQl1, mfma(aKh0, bQh1, Z)));
    float16 S11 = mfma(aKl1, bQh1, mfma(aKh1, bQl1, mfma(aKh1, bQh1, Z)));

    // exp2 + pack in register order; packed regs ARE the PV B-operand.
    unsigned p00[8], p01[8], p11[8];
    exp_pack<true >(S00, p00, m);  // t<32,  s<32: diag mask
    exp_pack<false>(S01, p01, m);  // t>=32, s<32: fully kept
    exp_pack<true >(S11, p11, m);  // t>=32, s>=32: diag mask

    // O' = V'.P : A = vb (m=d), B = packed P (n=t) -> D[d][t] token-per-lane.
    // Chunk pairing identical to r9; only the argument order is swapped
    // (both operands use the same lane/k-slot mapping - r4/r9 validated).
    float16 acc0 = mfma(vb[1], af(p00 + 4), mfma(vb[0], af(p00), Z));
    float16 acc1 = mfma(vb[3], af(p11 + 4),
                   mfma(vb[2], af(p11),
                   mfma(vb[1], af(p01 + 4),
                   mfma(vb[0], af(p01), Z))));

    // Redistribute via half-swap: lane(tloc,h=0) holds o0..3(tloc)=acc0[0..3]
    // and o0..3(tloc+32)=acc1[0..3]; lane(tloc,h=1) holds l(tloc)=acc0[0]
    // (m=4 -> r=0) and l(tloc+32)=acc1[0].
    const float e0 = __shfl_xor(loh ? acc1[0] : acc0[0], 32, 64);
    const float e1 = __shfl_xor(loh ? acc1[1] : acc0[1], 32, 64);
    const float e2 = __shfl_xor(loh ? acc1[2] : acc0[2], 32, 64);
    const float e3 = __shfl_xor(loh ? acc1[3] : acc0[3], 32, 64);
    const float o0r = loh ? acc0[0] : e0;
    const float o1r = loh ? acc0[1] : e1;
    const float o2r = loh ? acc0[2] : e2;
    const float o3r = loh ? acc0[3] : e3;
    const float lr  = loh ? e0 : acc1[0];

    const float invl = __builtin_amdgcn_rcpf(lr);
    const float o0 = o0r * invl, o1 = o1r * invl, o2 = o2r * invl, o3 = o3r * invl;

    // x += o @ Wq
    const float xa0 = x0i + o0*Wq00 + o1*Wq10 + o2*Wq20 + o3*Wq30;
    const float xa1 = x1i + o0*Wq01 + o1*Wq11 + o2*Wq21 + o3*Wq31;
    const float xa2 = x2i + o0*Wq02 + o1*Wq12 + o2*Wq22 + o3*Wq32;

    // MLP with RMSNorm 2
    const float r2 = __builtin_amdgcn_rsqf((xa0*xa0 + xa1*xa1 + xa2*xa2) * (1.0f/3.0f) + kEps);
    const float hh0 = xa0*r2*wl2_0, hh1 = xa1*r2*wl2_1, hh2 = xa2*r2*wl2_2;
    const float g0 = hh0*Wg00 + hh1*Wg01 + hh2*Wg02;
    const float g1 = hh0*Wg10 + hh1*Wg11 + hh2*Wg12;
    const float u0 = hh0*Wu00 + hh1*Wu01 + hh2*Wu02;
    const float u1 = hh0*Wu10 + hh1*Wu11 + hh2*Wu12;
    constexpr float kL2E = 1.4426950408889634f;
    const float f0 = g0 * __builtin_amdgcn_rcpf(1.0f + __builtin_amdgcn_exp2f(-g0 * kL2E)) * u0;
    const float f1 = g1 * __builtin_amdgcn_rcpf(1.0f + __builtin_amdgcn_exp2f(-g1 * kL2E)) * u1;
    const float xf0 = xa0 + f0*Wd00 + f1*Wd01;
    const float xf1 = xa1 + f0*Wd10 + f1*Wd11;
    const float xf2 = xa2 + f0*Wd20 + f1*Wd21;

    // Final RMSNorm; only comps 0,1 feed the logits
    const float rf = __builtin_amdgcn_rsqf((xf0*xf0 + xf1*xf1 + xf2*xf2) * (1.0f/3.0f) + kEps);
    const float y0 = xf0 * rf * wlf0;
    const float y1 = xf1 * rf * wlf1;

    // Logits from the LDS table (uniform b128 broadcast reads)
    const float4* tb4 = (const float4*)table_s;
    const float4 T0 = tb4[0], T1 = tb4[1], T2 = tb4[2], T3 = tb4[3], T4 = tb4[4];

    float2* op = (float2*)(out + (size_t)(row * 64 + lane) * kVocab);
    op[0] = float2{y0*T0.x + y1*T0.y, y0*T0.z + y1*T0.w};
    op[1] = float2{y0*T1.x + y1*T1.y, y0*T1.z + y1*T1.w};
    op[2] = float2{y0*T2.x + y1*T2.y, y0*T2.z + y1*T2.w};
    op[3] = float2{y0*T3.x + y1*T3.y, y0*T3.z + y1*T3.w};
    op[4] = float2{y0*T4.x + y1*T4.y, y0*T4.z + y1*T4.w};
}
}  // namespace

extern "C" void kernel_launch(void* const* d_in, const int* in_sizes, int n_in,
                              void* d_out, int out_size, void* d_ws, size_t ws_size,
                              hipStream_t stream) {
    (void)in_sizes; (void)n_in; (void)d_ws; (void)ws_size; (void)out_size;
    const int*   idx       = (const int*)  d_in[0];
    const float* arcA      = (const float*)d_in[1];
    const float* arcStart  = (const float*)d_in[2];
    const float* arcStride = (const float*)d_in[3];
    const float* w_ln1     = (const float*)d_in[4];
    const float* w_ln2     = (const float*)d_in[5];
    const float* w_lnf     = (const float*)d_in[6];
    const float* w_qn      = (const float*)d_in[7];
    const float* Wq        = (const float*)d_in[8];
    const float* Wk        = (const float*)d_in[9];
    const float* Wg        = (const float*)d_in[10];
    const float* Wu        = (const float*)d_in[11];
    const float* Wd        = (const float*)d_in[12];
    float* out = (float*)d_out;

    dim3 grid(4096), block(256);   // 16384 waves = 1 row/wave, exact cover
    hipLaunchKernelGGL(adder_model_kernel, grid, block, 0, stream,
                       idx, arcA, arcStart, arcStride,
                       w_ln1, w_ln2, w_lnf, w_qn, Wq, Wk, Wg, Wu, Wd, out);
}